// Round 11
// baseline (5092.731 us; speedup 1.0000x reference)
//
#include <hip/hip_runtime.h>
#include <math.h>

#define IN_DIM 8192
#define HID 128
#define NSTEPS 4096

typedef _Float16 f16x8 __attribute__((ext_vector_type(8)));
typedef float f32x4 __attribute__((ext_vector_type(4)));

__device__ __forceinline__ float sigm(float x) { return 1.f / (1.f + __expf(-x)); }
__device__ __forceinline__ float tanh_f(float x) {
    x = fminf(fmaxf(x, -15.f), 15.f);          // avoid inf/inf NaN
    float e = __expf(2.f * x);
    return (e - 1.f) / (e + 1.f);
}

// ---------------------------------------------------------------------------
// Kernel 1: M = W_enc @ W_dec  (128x128), cvec = W_enc@b_dec + b_enc,
//           e1 = W_enc@x0 + b_enc.  Grid: 128 blocks (one per row p), 128 thr.
// ---------------------------------------------------------------------------
__global__ __launch_bounds__(128) void k_precompute_M(
    const float* __restrict__ W_enc, const float* __restrict__ W_dec,
    const float* __restrict__ b_enc, const float* __restrict__ b_dec,
    const float* __restrict__ x0,
    float* __restrict__ M, float* __restrict__ cvec, float* __restrict__ e1)
{
    const int p = blockIdx.x;
    const int t = threadIdx.x;              // 0..127 (= output column q)
    __shared__ float wl[128];
    __shared__ float red[256];
    float m0 = 0.f, m1 = 0.f, m2 = 0.f, m3 = 0.f, cacc = 0.f, eacc = 0.f;
    for (int i0 = 0; i0 < IN_DIM; i0 += 128) {
        float w = W_enc[(size_t)p * IN_DIM + i0 + t];   // coalesced
        cacc = fmaf(w, b_dec[i0 + t], cacc);
        eacc = fmaf(w, x0[i0 + t], eacc);
        wl[t] = w;
        __syncthreads();
#pragma unroll 8
        for (int k = 0; k < 128; k += 4) {              // W_dec reads coalesced in t
            m0 = fmaf(wl[k],     W_dec[(size_t)(i0 + k) * HID + t], m0);
            m1 = fmaf(wl[k + 1], W_dec[(size_t)(i0 + k + 1) * HID + t], m1);
            m2 = fmaf(wl[k + 2], W_dec[(size_t)(i0 + k + 2) * HID + t], m2);
            m3 = fmaf(wl[k + 3], W_dec[(size_t)(i0 + k + 3) * HID + t], m3);
        }
        __syncthreads();
    }
    M[p * HID + t] = (m0 + m1) + (m2 + m3);
    red[t] = cacc; red[128 + t] = eacc;
    __syncthreads();
    for (int s = 64; s > 0; s >>= 1) {
        if (t < s) { red[t] += red[t + s]; red[128 + t] += red[128 + t + s]; }
        __syncthreads();
    }
    if (t == 0) { cvec[p] = red[0] + b_enc[p]; e1[p] = red[128] + b_enc[p]; }
}

// ---------------------------------------------------------------------------
// Kernel 2: G rows 0..383 = W_ih@M, rows 384..767 = W_hh (copy).
//           gb[0..383] = W_ih@cvec + bias, gb[384..767] = 0.
//           ig1 = W_ih@e1 + bias.  Grid: 768 blocks, 128 threads.
// ---------------------------------------------------------------------------
__global__ __launch_bounds__(128) void k_precompute_G(
    const float* __restrict__ W_ih, const float* __restrict__ W_hh,
    const float* __restrict__ bias, const float* __restrict__ M,
    const float* __restrict__ cvec, const float* __restrict__ e1,
    float* __restrict__ G, float* __restrict__ gb, float* __restrict__ ig1)
{
    const int r = blockIdx.x;
    const int q = threadIdx.x;
    if (r >= 384) {
        G[(size_t)r * HID + q] = W_hh[(size_t)(r - 384) * HID + q];
        if (q == 0) gb[r] = 0.f;
        return;
    }
    __shared__ float red[256];
    float a0 = 0.f, a1 = 0.f, a2 = 0.f, a3 = 0.f;
#pragma unroll 8
    for (int k = 0; k < HID; k += 4) {   // W_ih[r][k] scalar-uniform, M coalesced
        a0 = fmaf(W_ih[r * HID + k],     M[(k) * HID + q], a0);
        a1 = fmaf(W_ih[r * HID + k + 1], M[(k + 1) * HID + q], a1);
        a2 = fmaf(W_ih[r * HID + k + 2], M[(k + 2) * HID + q], a2);
        a3 = fmaf(W_ih[r * HID + k + 3], M[(k + 3) * HID + q], a3);
    }
    G[(size_t)r * HID + q] = (a0 + a1) + (a2 + a3);
    float wq = W_ih[r * HID + q];
    red[q] = wq * cvec[q];
    red[128 + q] = wq * e1[q];
    __syncthreads();
    for (int s = 64; s > 0; s >>= 1) {
        if (q < s) { red[q] += red[q + s]; red[128 + q] += red[128 + q + s]; }
        __syncthreads();
    }
    if (q == 0) { gb[r] = red[0] + bias[r]; ig1[r] = red[128] + bias[r]; }
}

// ---------------------------------------------------------------------------
// Kernel 2b: pack G into MFMA A-fragments (f16), UNIT-ALIGNED 8-wave layout.
// Wave w owns gate units 16w..16w+15 -> rows 128b+16w..+15 for b=0..5.
// Fragment (w,b,c): tile rows 128b+16w+(0..15), k-chunk c.
// A-layout (v_mfma_f32_16x16x32_f16): lane l elem i = A[l&15][8*(l>>4)+i].
// Gp[((w*24 + b*4 + c)*64 + l)*8 + i] = G[128b+16w+(l&15)][32c+8*(l>>4)+i].
// ---------------------------------------------------------------------------
__global__ __launch_bounds__(256) void k_pack(
    const float* __restrict__ G, _Float16* __restrict__ Gp)
{
    int id = blockIdx.x * 256 + threadIdx.x;   // 0..98303
    int i = id & 7;
    int l = (id >> 3) & 63;
    int frag = id >> 9;                        // 0..191 = w*24 + b*4 + c
    int c = frag & 3;
    int b = (frag >> 2) % 6;
    int w = frag / 24;
    int row = 128 * b + 16 * w + (l & 15);
    int k = 32 * c + ((l >> 4) << 3) + i;
    Gp[id] = (_Float16)G[row * HID + k];
}

// ---------------------------------------------------------------------------
// Kernel 3: sequential GRU scan, NO g round-trip. ONE block, 512 thr (8 waves,
// 2/SIMD). Wave w owns UNITS 16w..16w+15 = rows {128b+16w..+15}. With the
// D-map (verified in-kernel since R8: reg p <-> row 4*(l>>4)+p), lane l's
// accumulators d0..d5[p] hold ALL SIX g-components of unit u=16w+4*(l>>4)+p
// -> gates compute straight from MFMA outputs (16-lane redundancy is free).
// gb folds into the MFMA C-init. Cross-wave traffic = h' only (8 B/wave) into
// a parity-double-buffered h16 -> ONE raw barrier/step (no vmcnt drain; the
// global H store floats). Weights: 24 A-frags = 96 AGPR ("+a", R8 mechanism),
// ~90 VGPR; 186 <= 256 budget at launch_bounds(512,2).
// ---------------------------------------------------------------------------
#define WF24(F) F(0,0) F(0,1) F(0,2) F(0,3) F(1,0) F(1,1) F(1,2) F(1,3) \
                F(2,0) F(2,1) F(2,2) F(2,3) F(3,0) F(3,1) F(3,2) F(3,3) \
                F(4,0) F(4,1) F(4,2) F(4,3) F(5,0) F(5,1) F(5,2) F(5,3)

__global__ __launch_bounds__(512, 2) void k_recurrence(
    const _Float16* __restrict__ Gp, const float* __restrict__ gb,
    const float* __restrict__ ig1, const float* __restrict__ bias_n,
    float* __restrict__ H)
{
    const int t = threadIdx.x;           // 0..511
    const int l = t & 63;                // lane
    const int w = t >> 6;                // wave 0..7; units 16w..16w+15
    __shared__ _Float16 hbuf[2][HID];    // parity double-buffered h (256B each)

    // --- stationary weights: 24 MFMA A-fragments -> AGPRs ---
    const f16x8* gpb = (const f16x8*)Gp;
#define DECLW(b,c) f16x8 wf##b##c = gpb[(w * 24 + b * 4 + c) * 64 + l];
    WF24(DECLW)
#undef DECLW
#define PINW(b,c) asm volatile("" : "+a"(wf##b##c));
    WF24(PINW)
#undef PINW

    const int g4 = l >> 4;               // 16-lane group 0..3
    const int u4 = 16 * w + 4 * g4;      // this lane's units: u4..u4+3
    const bool writer = (l & 15) == 0;

    // per-lane constants: folded bias as MFMA C-init (blocks 0..2), bias_n
    const f32x4 cb0 = *(const f32x4*)&gb[u4];            // ir bias
    const f32x4 cb1 = *(const f32x4*)&gb[HID + u4];      // iz bias
    const f32x4 cb2 = *(const f32x4*)&gb[2 * HID + u4];  // in bias
    const float4 bnv = *(const float4*)&bias_n[u4];
    const f32x4 zero = {0.f, 0.f, 0.f, 0.f};

    float hp0, hp1, hp2, hp3;            // carried h for units u4..u4+3

    // prologue: step 1 from ig1 (h0 = 0 -> hg = 0), redundant per group
    {
        const float4 i0 = *(const float4*)&ig1[u4];
        const float4 i1 = *(const float4*)&ig1[HID + u4];
        const float4 i2 = *(const float4*)&ig1[2 * HID + u4];
#define PRO(p, ix, iz, in, bn, hp) { \
        float zg = sigm(iz); \
        float ng = tanh_f(fmaf(sigm(ix), bn, in)); \
        hp = ng - zg * ng; }
        PRO(0, i0.x, i1.x, i2.x, bnv.x, hp0)
        PRO(1, i0.y, i1.y, i2.y, bnv.y, hp1)
        PRO(2, i0.z, i1.z, i2.z, bnv.z, hp2)
        PRO(3, i0.w, i1.w, i2.w, bnv.w, hp3)
#undef PRO
        if (writer) {
            union { _Float16 h[4]; unsigned long long u; } pk;
            pk.h[0] = (_Float16)hp0; pk.h[1] = (_Float16)hp1;
            pk.h[2] = (_Float16)hp2; pk.h[3] = (_Float16)hp3;
            *(unsigned long long*)&hbuf[1][u4] = pk.u;    // h for step st=1
            float4 st4 = { hp0, hp1, hp2, hp3 };
            *(float4*)&H[u4] = st4;                       // H[0] = h1
        }
    }
    __syncthreads();

    for (int st = 1; st < NSTEPS; ++st) {
        const char* cb = (const char*)&hbuf[st & 1][0];
        // B-fragments: chunk c, lane l -> h[32c + 8*g4 + i] (group-bcast 16B)
        f16x8 b0 = *(const f16x8*)(cb + 16 * g4);
        f16x8 b1 = *(const f16x8*)(cb + 16 * g4 + 64);
        f16x8 b2 = *(const f16x8*)(cb + 16 * g4 + 128);
        f16x8 b3 = *(const f16x8*)(cb + 16 * g4 + 192);
        // 6 independent 4-deep chains; C-init = folded bias (blocks 0..2)
#define TILE(b, cinit) \
        f32x4 d##b = __builtin_amdgcn_mfma_f32_16x16x32_f16(wf##b##0, b0, cinit, 0, 0, 0); \
        d##b = __builtin_amdgcn_mfma_f32_16x16x32_f16(wf##b##1, b1, d##b, 0, 0, 0); \
        d##b = __builtin_amdgcn_mfma_f32_16x16x32_f16(wf##b##2, b2, d##b, 0, 0, 0); \
        d##b = __builtin_amdgcn_mfma_f32_16x16x32_f16(wf##b##3, b3, d##b, 0, 0, 0);
        TILE(0, cb0) TILE(1, cb1) TILE(2, cb2)
        TILE(3, zero) TILE(4, zero) TILE(5, zero)
#undef TILE
        // gates straight from accumulators: unit u4+p lives in d*[p]
#define GATE(p, bn, hp) { \
        float rg = sigm(d0[p] + d3[p]); \
        float zg = sigm(d1[p] + d4[p]); \
        float ng = tanh_f(d2[p] + rg * (d5[p] + bn)); \
        hp = ng + zg * (hp - ng); }
        GATE(0, bnv.x, hp0)
        GATE(1, bnv.y, hp1)
        GATE(2, bnv.z, hp2)
        GATE(3, bnv.w, hp3)
#undef GATE
        if (writer) {
            union { _Float16 h[4]; unsigned long long u; } pk;
            pk.h[0] = (_Float16)hp0; pk.h[1] = (_Float16)hp1;
            pk.h[2] = (_Float16)hp2; pk.h[3] = (_Float16)hp3;
            *(unsigned long long*)&hbuf[(st + 1) & 1][u4] = pk.u;
            float4 st4 = { hp0, hp1, hp2, hp3 };
            *(float4*)&H[(size_t)st * HID + u4] = st4;    // never drained
        }
        // LDS-visibility barrier only (no vmcnt drain)
        asm volatile("s_waitcnt lgkmcnt(0)" ::: "memory");
        __builtin_amdgcn_s_barrier();
        __builtin_amdgcn_sched_barrier(0);
    }
}

// ---------------------------------------------------------------------------
// Kernel 4: out[t][i] = dot(H[t][:], W_dec[i][:]) + b_dec[i]
// GEMM M=4096(t) N=8192(i) K=128, fp32 vector. 64x64 tiles, 256 threads,
// 4x4 micro-tile (strided by 16), XOR-swizzled LDS (64KB total, conflict-free).
// ---------------------------------------------------------------------------
__global__ __launch_bounds__(256) void k_decode(
    const float* __restrict__ H, const float* __restrict__ W_dec,
    const float* __restrict__ b_dec, float* __restrict__ out)
{
    __shared__ float4 As[64 * 32];   // [t][k4], k4 XOR-swizzled by (t&7)
    __shared__ float4 Bs[64 * 32];   // [i][k4]
    const int tid = threadIdx.x;
    const int t0 = blockIdx.y * 64;
    const int i0 = blockIdx.x * 64;
#pragma unroll 8
    for (int j = 0; j < 8; ++j) {
        int f = tid + 256 * j;        // 0..2047 float4s, coalesced
        int t = f >> 5;
        int k4 = f & 31;
        int sw = k4 ^ (t & 7);
        As[t * 32 + sw] = *(const float4*)(H + (size_t)(t0 + t) * HID + 4 * k4);
        Bs[t * 32 + sw] = *(const float4*)(W_dec + (size_t)(i0 + t) * HID + 4 * k4);
    }
    __syncthreads();
    const int tx = tid & 15, ty = tid >> 4;
    const int xa = ty & 7, xb = tx & 7;
    float acc[4][4] = {{0.f}};
#pragma unroll 8
    for (int k4 = 0; k4 < 32; ++k4) {
        float4 a[4], b[4];
        int ia = k4 ^ xa, ib = k4 ^ xb;
#pragma unroll
        for (int u = 0; u < 4; ++u) a[u] = As[(ty + 16 * u) * 32 + ia];
#pragma unroll
        for (int v = 0; v < 4; ++v) b[v] = Bs[(tx + 16 * v) * 32 + ib];
#pragma unroll
        for (int u = 0; u < 4; ++u)
#pragma unroll
            for (int v = 0; v < 4; ++v) {
                acc[u][v] = fmaf(a[u].x, b[v].x, acc[u][v]);
                acc[u][v] = fmaf(a[u].y, b[v].y, acc[u][v]);
                acc[u][v] = fmaf(a[u].z, b[v].z, acc[u][v]);
                acc[u][v] = fmaf(a[u].w, b[v].w, acc[u][v]);
            }
    }
#pragma unroll
    for (int u = 0; u < 4; ++u) {
        int t = t0 + ty + 16 * u;
#pragma unroll
        for (int v = 0; v < 4; ++v) {
            int i = i0 + tx + 16 * v;
            out[(size_t)t * IN_DIM + i] = acc[u][v] + b_dec[i];
        }
    }
}

// ---------------------------------------------------------------------------
extern "C" void kernel_launch(void* const* d_in, const int* in_sizes, int n_in,
                              void* d_out, int out_size, void* d_ws, size_t ws_size,
                              hipStream_t stream)
{
    const float* x0     = (const float*)d_in[0];
    const float* W_enc  = (const float*)d_in[1];
    const float* b_enc  = (const float*)d_in[2];
    const float* W_ih   = (const float*)d_in[3];
    const float* W_hh   = (const float*)d_in[4];
    const float* bias   = (const float*)d_in[5];
    const float* bias_n = (const float*)d_in[6];
    const float* W_dec  = (const float*)d_in[7];
    const float* b_dec  = (const float*)d_in[8];
    float* out = (float*)d_out;

    // workspace layout (floats): ~2.76 MB
    float* ws   = (float*)d_ws;
    float* M    = ws;                 // 16384
    float* cvec = ws + 16384;         // 128
    float* e1   = ws + 16512;         // 128
    float* ig1  = ws + 16640;         // 384
    float* gb   = ws + 17024;         // 768
    float* G    = ws + 17792;         // 98304   (16B-aligned)
    float* H    = ws + 116096;        // 524288  (16B-aligned)
    _Float16* Gp = (_Float16*)(ws + 640384);   // 98304 f16 (192 KB)

    k_precompute_M<<<128, 128, 0, stream>>>(W_enc, W_dec, b_enc, b_dec, x0, M, cvec, e1);
    k_precompute_G<<<768, 128, 0, stream>>>(W_ih, W_hh, bias, M, cvec, e1, G, gb, ig1);
    k_pack<<<384, 256, 0, stream>>>(G, Gp);
    k_recurrence<<<1, 512, 0, stream>>>(Gp, gb, ig1, bias_n, H);
    dim3 grid(IN_DIM / 64, NSTEPS / 64);
    k_decode<<<grid, 256, 0, stream>>>(H, W_dec, b_dec, out);
}

// Round 12
// 3812.640 us; speedup vs baseline: 1.3357x; 1.3357x over previous
//
#include <hip/hip_runtime.h>
#include <math.h>

#define IN_DIM 8192
#define HID 128
#define NSTEPS 4096

typedef _Float16 f16x8 __attribute__((ext_vector_type(8)));
typedef float f32x4 __attribute__((ext_vector_type(4)));

__device__ __forceinline__ float sigm(float x) { return 1.f / (1.f + __expf(-x)); }
__device__ __forceinline__ float tanh_f(float x) {
    x = fminf(fmaxf(x, -15.f), 15.f);          // avoid inf/inf NaN
    float e = __expf(2.f * x);
    return (e - 1.f) / (e + 1.f);
}

// ---------------------------------------------------------------------------
// Kernel 1: M = W_enc @ W_dec  (128x128), cvec = W_enc@b_dec + b_enc,
//           e1 = W_enc@x0 + b_enc.  Grid: 128 blocks (one per row p), 128 thr.
// ---------------------------------------------------------------------------
__global__ __launch_bounds__(128) void k_precompute_M(
    const float* __restrict__ W_enc, const float* __restrict__ W_dec,
    const float* __restrict__ b_enc, const float* __restrict__ b_dec,
    const float* __restrict__ x0,
    float* __restrict__ M, float* __restrict__ cvec, float* __restrict__ e1)
{
    const int p = blockIdx.x;
    const int t = threadIdx.x;              // 0..127 (= output column q)
    __shared__ float wl[128];
    __shared__ float red[256];
    float m0 = 0.f, m1 = 0.f, m2 = 0.f, m3 = 0.f, cacc = 0.f, eacc = 0.f;
    for (int i0 = 0; i0 < IN_DIM; i0 += 128) {
        float w = W_enc[(size_t)p * IN_DIM + i0 + t];   // coalesced
        cacc = fmaf(w, b_dec[i0 + t], cacc);
        eacc = fmaf(w, x0[i0 + t], eacc);
        wl[t] = w;
        __syncthreads();
#pragma unroll 8
        for (int k = 0; k < 128; k += 4) {              // W_dec reads coalesced in t
            m0 = fmaf(wl[k],     W_dec[(size_t)(i0 + k) * HID + t], m0);
            m1 = fmaf(wl[k + 1], W_dec[(size_t)(i0 + k + 1) * HID + t], m1);
            m2 = fmaf(wl[k + 2], W_dec[(size_t)(i0 + k + 2) * HID + t], m2);
            m3 = fmaf(wl[k + 3], W_dec[(size_t)(i0 + k + 3) * HID + t], m3);
        }
        __syncthreads();
    }
    M[p * HID + t] = (m0 + m1) + (m2 + m3);
    red[t] = cacc; red[128 + t] = eacc;
    __syncthreads();
    for (int s = 64; s > 0; s >>= 1) {
        if (t < s) { red[t] += red[t + s]; red[128 + t] += red[128 + t + s]; }
        __syncthreads();
    }
    if (t == 0) { cvec[p] = red[0] + b_enc[p]; e1[p] = red[128] + b_enc[p]; }
}

// ---------------------------------------------------------------------------
// Kernel 2: G rows 0..383 = W_ih@M, rows 384..767 = W_hh (copy).
//           gb[0..383] = W_ih@cvec + bias, gb[384..767] = 0.
//           ig1 = W_ih@e1 + bias.  Grid: 768 blocks, 128 threads.
// ---------------------------------------------------------------------------
__global__ __launch_bounds__(128) void k_precompute_G(
    const float* __restrict__ W_ih, const float* __restrict__ W_hh,
    const float* __restrict__ bias, const float* __restrict__ M,
    const float* __restrict__ cvec, const float* __restrict__ e1,
    float* __restrict__ G, float* __restrict__ gb, float* __restrict__ ig1)
{
    const int r = blockIdx.x;
    const int q = threadIdx.x;
    if (r >= 384) {
        G[(size_t)r * HID + q] = W_hh[(size_t)(r - 384) * HID + q];
        if (q == 0) gb[r] = 0.f;
        return;
    }
    __shared__ float red[256];
    float a0 = 0.f, a1 = 0.f, a2 = 0.f, a3 = 0.f;
#pragma unroll 8
    for (int k = 0; k < HID; k += 4) {   // W_ih[r][k] scalar-uniform, M coalesced
        a0 = fmaf(W_ih[r * HID + k],     M[(k) * HID + q], a0);
        a1 = fmaf(W_ih[r * HID + k + 1], M[(k + 1) * HID + q], a1);
        a2 = fmaf(W_ih[r * HID + k + 2], M[(k + 2) * HID + q], a2);
        a3 = fmaf(W_ih[r * HID + k + 3], M[(k + 3) * HID + q], a3);
    }
    G[(size_t)r * HID + q] = (a0 + a1) + (a2 + a3);
    float wq = W_ih[r * HID + q];
    red[q] = wq * cvec[q];
    red[128 + q] = wq * e1[q];
    __syncthreads();
    for (int s = 64; s > 0; s >>= 1) {
        if (q < s) { red[q] += red[q + s]; red[128 + q] += red[128 + q + s]; }
        __syncthreads();
    }
    if (q == 0) { gb[r] = red[0] + bias[r]; ig1[r] = red[128] + bias[r]; }
}

// ---------------------------------------------------------------------------
// Kernel 2b: pack G (f32, 768x128 row-major) into MFMA A-fragments (f16).
// Fragment (w,j,c): wave w, tile j (rows 48w+16j..+15), K-chunk c (k=32c..+31).
// A-layout for v_mfma_f32_16x16x32_f16: lane l holds A[row=l&15][k=(l>>4)*8+i].
// ---------------------------------------------------------------------------
__global__ __launch_bounds__(256) void k_pack(
    const float* __restrict__ G, _Float16* __restrict__ Gp)
{
    int id = blockIdx.x * 256 + threadIdx.x;   // 0..98303
    int i = id & 7;
    int l = (id >> 3) & 63;
    int frag = id >> 9;                        // 0..191 = w*12 + j*4 + c
    int c = frag & 3;
    int j = (frag >> 2) % 3;
    int w = frag / 12;
    int row = 48 * w + 16 * j + (l & 15);
    int k = 32 * c + ((l >> 4) << 3) + i;
    Gp[id] = (_Float16)G[row * HID + k];
}

// ---------------------------------------------------------------------------
// Kernel 3: sequential GRU scan via MFMA. ONE block, 1024 threads (16 waves).
// EXACT R8 structure (best measured: 2016 cyc/step) with two surgical fixes:
// (1) RAW barriers (lgkmcnt(0) + s_barrier) — __syncthreads lowers to
//     s_waitcnt vmcnt(0) before s_barrier (m97), which made every step wait
//     for the gate waves' HBM H-store to COMPLETE (~900 cyc, m126). R6 and R8
//     landing at identical ~2010 cyc/step despite different compute engines
//     fingered this structure-invariant drain.
// (2) H-store OFFLOAD: gate waves (0-1) write h' f32 into a parity LDS ring;
//     waves 2-3 (idle in R8's gate phase) global-store the PREVIOUS step's
//     row. Gate waves never issue VMEM; storers' in-flight stores are never
//     drained at a barrier (raw barriers don't touch vmcnt).
// Weights: 12 A-frags = 48 AGPR ("+a", R8-verified resident mechanism).
// ---------------------------------------------------------------------------
#define WF(F) F(0,0) F(0,1) F(0,2) F(0,3) F(1,0) F(1,1) F(1,2) F(1,3) \
              F(2,0) F(2,1) F(2,2) F(2,3)

__global__ __launch_bounds__(1024, 4) void k_recurrence(
    const _Float16* __restrict__ Gp, const float* __restrict__ gb,
    const float* __restrict__ ig1, const float* __restrict__ bias_n,
    float* __restrict__ H)
{
    const int t = threadIdx.x;           // 0..1023
    const int l = t & 63;                // lane
    const int w = t >> 6;                // wave 0..15; rows 48w..48w+47
    __shared__ _Float16 h16[HID];        // 256 B (B-fragment broadcast source)
    __shared__ float h32r[2][HID];       // f32 h ring for the H-store offload
    __shared__ float g_lds[6 * HID];
    __shared__ float gb_lds[6 * HID];

    if (t < 6 * HID) gb_lds[t] = gb[t];

    // --- stationary weights: 12 MFMA A-fragments -> AGPRs ---
    const f16x8* gpb = (const f16x8*)Gp;
#define DECLW(j,c) f16x8 wf##j##c = gpb[(w * 12 + j * 4 + c) * 64 + l];
    WF(DECLW)
#undef DECLW
#define PINW(j,c) asm volatile("" : "+a"(wf##j##c));
    WF(PINW)
#undef PINW

    const float bnr = (t < HID) ? bias_n[t] : 0.f;
    float hreg = 0.f;

    // step 1: h0 = 0 => hg = 0, use precomputed ig1
    if (t < HID) {
        float ir = ig1[t], iz = ig1[HID + t], inn = ig1[2 * HID + t];
        float rg = sigm(ir), zg = sigm(iz);
        float ng = tanh_f(fmaf(rg, bnr, inn));
        hreg = ng - zg * ng;             // n + z*(0 - n)
        h16[t] = (_Float16)hreg;
        h32r[0][t] = hreg;               // ring slot for H[0]
    }
    __syncthreads();

    const int g4 = l >> 4;                       // 16-lane group 0..3
    const char* hbase = (const char*)h16 + g4 * 16;
    const int pbase = 48 * w + (g4 << 2);        // g-write row base (j=0)
    const float4 gbv0 = *(const float4*)&gb_lds[pbase];
    const float4 gbv1 = *(const float4*)&gb_lds[pbase + 16];
    const float4 gbv2 = *(const float4*)&gb_lds[pbase + 32];
    const bool writer = (l & 15) == 0;
    const f32x4 zero = {0.f, 0.f, 0.f, 0.f};

    for (int st = 1; st < NSTEPS; ++st) {
        // B-fragments: h chunk c, lane l -> h[32c + 8*(l>>4) + i] (16B bcast)
        f16x8 b0 = *(const f16x8*)(hbase);
        f16x8 b1 = *(const f16x8*)(hbase + 64);
        f16x8 b2 = *(const f16x8*)(hbase + 128);
        f16x8 b3 = *(const f16x8*)(hbase + 192);
        // R8-original: 3 independent 4-deep MFMA chains
        f32x4 d0 = __builtin_amdgcn_mfma_f32_16x16x32_f16(wf00, b0, zero, 0, 0, 0);
        f32x4 d1 = __builtin_amdgcn_mfma_f32_16x16x32_f16(wf10, b0, zero, 0, 0, 0);
        f32x4 d2 = __builtin_amdgcn_mfma_f32_16x16x32_f16(wf20, b0, zero, 0, 0, 0);
        d0 = __builtin_amdgcn_mfma_f32_16x16x32_f16(wf01, b1, d0, 0, 0, 0);
        d1 = __builtin_amdgcn_mfma_f32_16x16x32_f16(wf11, b1, d1, 0, 0, 0);
        d2 = __builtin_amdgcn_mfma_f32_16x16x32_f16(wf21, b1, d2, 0, 0, 0);
        d0 = __builtin_amdgcn_mfma_f32_16x16x32_f16(wf02, b2, d0, 0, 0, 0);
        d1 = __builtin_amdgcn_mfma_f32_16x16x32_f16(wf12, b2, d1, 0, 0, 0);
        d2 = __builtin_amdgcn_mfma_f32_16x16x32_f16(wf22, b2, d2, 0, 0, 0);
        d0 = __builtin_amdgcn_mfma_f32_16x16x32_f16(wf03, b3, d0, 0, 0, 0);
        d1 = __builtin_amdgcn_mfma_f32_16x16x32_f16(wf13, b3, d1, 0, 0, 0);
        d2 = __builtin_amdgcn_mfma_f32_16x16x32_f16(wf23, b3, d2, 0, 0, 0);
        if (writer) {                    // lanes 0,16,32,48: rows pbase..+3
            float4 v0 = { d0[0] + gbv0.x, d0[1] + gbv0.y, d0[2] + gbv0.z, d0[3] + gbv0.w };
            float4 v1 = { d1[0] + gbv1.x, d1[1] + gbv1.y, d1[2] + gbv1.z, d1[3] + gbv1.w };
            float4 v2 = { d2[0] + gbv2.x, d2[1] + gbv2.y, d2[2] + gbv2.z, d2[3] + gbv2.w };
            *(float4*)&g_lds[pbase]      = v0;
            *(float4*)&g_lds[pbase + 16] = v1;
            *(float4*)&g_lds[pbase + 32] = v2;
        }
        // raw barrier: LDS visibility only, NO vmcnt drain
        asm volatile("s_waitcnt lgkmcnt(0)" ::: "memory");
        __builtin_amdgcn_s_barrier();
        if (t < HID) {                   // gate waves 0,1
            float ir = g_lds[t],           iz = g_lds[HID + t],     inn = g_lds[2 * HID + t];
            float hr = g_lds[3 * HID + t], hz = g_lds[4 * HID + t], hn = g_lds[5 * HID + t];
            float rg = sigm(ir + hr);
            float zg = sigm(iz + hz);
            float ng = tanh_f(inn + rg * (hn + bnr));
            float hnew = ng + zg * (hreg - ng);
            hreg = hnew;
            h16[t] = (_Float16)hnew;
            h32r[st & 1][t] = hnew;      // ring slot for H[st]
        } else if (t < 2 * HID) {        // storer waves 2,3: H[st-1] offload
            int u = t - HID;
            H[(size_t)(st - 1) * HID + u] = h32r[(st - 1) & 1][u];
        }
        asm volatile("s_waitcnt lgkmcnt(0)" ::: "memory");
        __builtin_amdgcn_s_barrier();
    }
    // final row: h of step NSTEPS-1 sits in the ring
    if (t >= HID && t < 2 * HID) {
        int u = t - HID;
        H[(size_t)(NSTEPS - 1) * HID + u] = h32r[(NSTEPS - 1) & 1][u];
    }
}

// ---------------------------------------------------------------------------
// Kernel 4: out[t][i] = dot(H[t][:], W_dec[i][:]) + b_dec[i]
// GEMM M=4096(t) N=8192(i) K=128, fp32 vector. 64x64 tiles, 256 threads,
// 4x4 micro-tile (strided by 16), XOR-swizzled LDS (64KB total, conflict-free).
// ---------------------------------------------------------------------------
__global__ __launch_bounds__(256) void k_decode(
    const float* __restrict__ H, const float* __restrict__ W_dec,
    const float* __restrict__ b_dec, float* __restrict__ out)
{
    __shared__ float4 As[64 * 32];   // [t][k4], k4 XOR-swizzled by (t&7)
    __shared__ float4 Bs[64 * 32];   // [i][k4]
    const int tid = threadIdx.x;
    const int t0 = blockIdx.y * 64;
    const int i0 = blockIdx.x * 64;
#pragma unroll 8
    for (int j = 0; j < 8; ++j) {
        int f = tid + 256 * j;        // 0..2047 float4s, coalesced
        int t = f >> 5;
        int k4 = f & 31;
        int sw = k4 ^ (t & 7);
        As[t * 32 + sw] = *(const float4*)(H + (size_t)(t0 + t) * HID + 4 * k4);
        Bs[t * 32 + sw] = *(const float4*)(W_dec + (size_t)(i0 + t) * HID + 4 * k4);
    }
    __syncthreads();
    const int tx = tid & 15, ty = tid >> 4;
    const int xa = ty & 7, xb = tx & 7;
    float acc[4][4] = {{0.f}};
#pragma unroll 8
    for (int k4 = 0; k4 < 32; ++k4) {
        float4 a[4], b[4];
        int ia = k4 ^ xa, ib = k4 ^ xb;
#pragma unroll
        for (int u = 0; u < 4; ++u) a[u] = As[(ty + 16 * u) * 32 + ia];
#pragma unroll
        for (int v = 0; v < 4; ++v) b[v] = Bs[(tx + 16 * v) * 32 + ib];
#pragma unroll
        for (int u = 0; u < 4; ++u)
#pragma unroll
            for (int v = 0; v < 4; ++v) {
                acc[u][v] = fmaf(a[u].x, b[v].x, acc[u][v]);
                acc[u][v] = fmaf(a[u].y, b[v].y, acc[u][v]);
                acc[u][v] = fmaf(a[u].z, b[v].z, acc[u][v]);
                acc[u][v] = fmaf(a[u].w, b[v].w, acc[u][v]);
            }
    }
#pragma unroll
    for (int u = 0; u < 4; ++u) {
        int t = t0 + ty + 16 * u;
#pragma unroll
        for (int v = 0; v < 4; ++v) {
            int i = i0 + tx + 16 * v;
            out[(size_t)t * IN_DIM + i] = acc[u][v] + b_dec[i];
        }
    }
}

// ---------------------------------------------------------------------------
extern "C" void kernel_launch(void* const* d_in, const int* in_sizes, int n_in,
                              void* d_out, int out_size, void* d_ws, size_t ws_size,
                              hipStream_t stream)
{
    const float* x0     = (const float*)d_in[0];
    const float* W_enc  = (const float*)d_in[1];
    const float* b_enc  = (const float*)d_in[2];
    const float* W_ih   = (const float*)d_in[3];
    const float* W_hh   = (const float*)d_in[4];
    const float* bias   = (const float*)d_in[5];
    const float* bias_n = (const float*)d_in[6];
    const float* W_dec  = (const float*)d_in[7];
    const float* b_dec  = (const float*)d_in[8];
    float* out = (float*)d_out;

    // workspace layout (floats): ~2.76 MB
    float* ws   = (float*)d_ws;
    float* M    = ws;                 // 16384
    float* cvec = ws + 16384;         // 128
    float* e1   = ws + 16512;         // 128
    float* ig1  = ws + 16640;         // 384
    float* gb   = ws + 17024;         // 768
    float* G    = ws + 17792;         // 98304   (16B-aligned)
    float* H    = ws + 116096;        // 524288  (16B-aligned)
    _Float16* Gp = (_Float16*)(ws + 640384);   // 98304 f16 (192 KB)

    k_precompute_M<<<128, 128, 0, stream>>>(W_enc, W_dec, b_enc, b_dec, x0, M, cvec, e1);
    k_precompute_G<<<768, 128, 0, stream>>>(W_ih, W_hh, bias, M, cvec, e1, G, gb, ig1);
    k_pack<<<384, 256, 0, stream>>>(G, Gp);
    k_recurrence<<<1, 1024, 0, stream>>>(Gp, gb, ig1, bias_n, H);
    dim3 grid(IN_DIM / 64, NSTEPS / 64);
    k_decode<<<grid, 256, 0, stream>>>(H, W_dec, b_dec, out);
}

// Round 13
// 2983.673 us; speedup vs baseline: 1.7069x; 1.2778x over previous
//
#include <hip/hip_runtime.h>
#include <math.h>

#define IN_DIM 8192
#define HID 128
#define NSTEPS 4096

typedef _Float16 f16x8 __attribute__((ext_vector_type(8)));
typedef float f32x4 __attribute__((ext_vector_type(4)));

__device__ __forceinline__ float sigm(float x) { return 1.f / (1.f + __expf(-x)); }
__device__ __forceinline__ float tanh_f(float x) {
    x = fminf(fmaxf(x, -15.f), 15.f);          // avoid inf/inf NaN
    float e = __expf(2.f * x);
    return (e - 1.f) / (e + 1.f);
}

// ---------------------------------------------------------------------------
// Kernel 1: M = W_enc @ W_dec  (128x128), cvec = W_enc@b_dec + b_enc,
//           e1 = W_enc@x0 + b_enc.  Grid: 128 blocks (one per row p), 128 thr.
// ---------------------------------------------------------------------------
__global__ __launch_bounds__(128) void k_precompute_M(
    const float* __restrict__ W_enc, const float* __restrict__ W_dec,
    const float* __restrict__ b_enc, const float* __restrict__ b_dec,
    const float* __restrict__ x0,
    float* __restrict__ M, float* __restrict__ cvec, float* __restrict__ e1)
{
    const int p = blockIdx.x;
    const int t = threadIdx.x;              // 0..127 (= output column q)
    __shared__ float wl[128];
    __shared__ float red[256];
    float m0 = 0.f, m1 = 0.f, m2 = 0.f, m3 = 0.f, cacc = 0.f, eacc = 0.f;
    for (int i0 = 0; i0 < IN_DIM; i0 += 128) {
        float w = W_enc[(size_t)p * IN_DIM + i0 + t];   // coalesced
        cacc = fmaf(w, b_dec[i0 + t], cacc);
        eacc = fmaf(w, x0[i0 + t], eacc);
        wl[t] = w;
        __syncthreads();
#pragma unroll 8
        for (int k = 0; k < 128; k += 4) {              // W_dec reads coalesced in t
            m0 = fmaf(wl[k],     W_dec[(size_t)(i0 + k) * HID + t], m0);
            m1 = fmaf(wl[k + 1], W_dec[(size_t)(i0 + k + 1) * HID + t], m1);
            m2 = fmaf(wl[k + 2], W_dec[(size_t)(i0 + k + 2) * HID + t], m2);
            m3 = fmaf(wl[k + 3], W_dec[(size_t)(i0 + k + 3) * HID + t], m3);
        }
        __syncthreads();
    }
    M[p * HID + t] = (m0 + m1) + (m2 + m3);
    red[t] = cacc; red[128 + t] = eacc;
    __syncthreads();
    for (int s = 64; s > 0; s >>= 1) {
        if (t < s) { red[t] += red[t + s]; red[128 + t] += red[128 + t + s]; }
        __syncthreads();
    }
    if (t == 0) { cvec[p] = red[0] + b_enc[p]; e1[p] = red[128] + b_enc[p]; }
}

// ---------------------------------------------------------------------------
// Kernel 2: G rows 0..383 = W_ih@M, rows 384..767 = W_hh (copy).
//           gb[0..383] = W_ih@cvec + bias, gb[384..767] = 0.
//           ig1 = W_ih@e1 + bias.  Grid: 768 blocks, 128 threads.
// ---------------------------------------------------------------------------
__global__ __launch_bounds__(128) void k_precompute_G(
    const float* __restrict__ W_ih, const float* __restrict__ W_hh,
    const float* __restrict__ bias, const float* __restrict__ M,
    const float* __restrict__ cvec, const float* __restrict__ e1,
    float* __restrict__ G, float* __restrict__ gb, float* __restrict__ ig1)
{
    const int r = blockIdx.x;
    const int q = threadIdx.x;
    if (r >= 384) {
        G[(size_t)r * HID + q] = W_hh[(size_t)(r - 384) * HID + q];
        if (q == 0) gb[r] = 0.f;
        return;
    }
    __shared__ float red[256];
    float a0 = 0.f, a1 = 0.f, a2 = 0.f, a3 = 0.f;
#pragma unroll 8
    for (int k = 0; k < HID; k += 4) {   // W_ih[r][k] scalar-uniform, M coalesced
        a0 = fmaf(W_ih[r * HID + k],     M[(k) * HID + q], a0);
        a1 = fmaf(W_ih[r * HID + k + 1], M[(k + 1) * HID + q], a1);
        a2 = fmaf(W_ih[r * HID + k + 2], M[(k + 2) * HID + q], a2);
        a3 = fmaf(W_ih[r * HID + k + 3], M[(k + 3) * HID + q], a3);
    }
    G[(size_t)r * HID + q] = (a0 + a1) + (a2 + a3);
    float wq = W_ih[r * HID + q];
    red[q] = wq * cvec[q];
    red[128 + q] = wq * e1[q];
    __syncthreads();
    for (int s = 64; s > 0; s >>= 1) {
        if (q < s) { red[q] += red[q + s]; red[128 + q] += red[128 + q + s]; }
        __syncthreads();
    }
    if (q == 0) { gb[r] = red[0] + bias[r]; ig1[r] = red[128] + bias[r]; }
}

// ---------------------------------------------------------------------------
// Kernel 2b: pack G into MFMA A-fragments (f16), UNIT-ALIGNED 8-wave layout.
// Wave w owns gate units 16w..16w+15 -> rows 128b+16w..+15 for b=0..5.
// A-layout (v_mfma_f32_16x16x32_f16): lane l elem i = A[l&15][8*(l>>4)+i].
// Gp[((w*24 + b*4 + c)*64 + l)*8 + i] = G[128b+16w+(l&15)][32c+8*(l>>4)+i].
// ---------------------------------------------------------------------------
__global__ __launch_bounds__(256) void k_pack(
    const float* __restrict__ G, _Float16* __restrict__ Gp)
{
    int id = blockIdx.x * 256 + threadIdx.x;   // 0..98303
    int i = id & 7;
    int l = (id >> 3) & 63;
    int frag = id >> 9;                        // 0..191 = w*24 + b*4 + c
    int c = frag & 3;
    int b = (frag >> 2) % 6;
    int w = frag / 24;
    int row = 128 * b + 16 * w + (l & 15);
    int k = 32 * c + ((l >> 4) << 3) + i;
    Gp[id] = (_Float16)G[row * HID + k];
}

// ---------------------------------------------------------------------------
// Kernel 3: sequential GRU scan, gates-from-accumulators. ONE block, 512 thr
// (8 waves, 2/SIMD). Wave w owns UNITS 16w..16w+15 (rows {128b+16w..+15}).
// D-map (m89, in-kernel verified since R8): lane l reg p = row 4*(l>>4)+p,
// col l&15 (all cols equal since B cols are replicated h). So lane l's d0..d5
// hold all 6 g-components of unit 16w+4*(l>>4)+p.
// R13 vs R11 (which was 2810 cyc/step, VALUBusy 0.30): each lane now handles
// ONE unit (p = l&3, 3 hoisted cndmask selects per accumulator) instead of 4
// serially -> gate VALU 128->~50 insts/lane; no sched_barrier; plain
// __syncthreads (R12 proved the vmcnt drain is free). One barrier per step,
// parity-double-buffered 512 B hbuf (R11-verified race-free).
// Weights: 24 A-frags = 96 AGPR ("+a", R8-verified resident mechanism).
// ---------------------------------------------------------------------------
#define WF24(F) F(0,0) F(0,1) F(0,2) F(0,3) F(1,0) F(1,1) F(1,2) F(1,3) \
                F(2,0) F(2,1) F(2,2) F(2,3) F(3,0) F(3,1) F(3,2) F(3,3) \
                F(4,0) F(4,1) F(4,2) F(4,3) F(5,0) F(5,1) F(5,2) F(5,3)

__global__ __launch_bounds__(512, 2) void k_recurrence(
    const _Float16* __restrict__ Gp, const float* __restrict__ gb,
    const float* __restrict__ ig1, const float* __restrict__ bias_n,
    float* __restrict__ H)
{
    const int t = threadIdx.x;           // 0..511
    const int l = t & 63;                // lane
    const int w = t >> 6;                // wave 0..7; units 16w..16w+15
    __shared__ _Float16 hbuf[2][HID];    // parity double-buffered h (256B each)

    // --- stationary weights: 24 MFMA A-fragments -> AGPRs ---
    const f16x8* gpb = (const f16x8*)Gp;
#define DECLW(b,c) f16x8 wf##b##c = gpb[(w * 24 + b * 4 + c) * 64 + l];
    WF24(DECLW)
#undef DECLW
#define PINW(b,c) asm volatile("" : "+a"(wf##b##c));
    WF24(PINW)
#undef PINW

    const int g4 = l >> 4;               // 16-lane group 0..3
    const int ul = 16 * w + 4 * g4 + (l & 3);   // this lane's gate unit
    const bool writer = (l & 12) == 0;   // 16 writers/wave, one per unit

    // per-lane scalars for unit ul
    const float gb0 = gb[ul];
    const float gb1 = gb[HID + ul];
    const float gb2 = gb[2 * HID + ul];
    const float bnr = bias_n[ul];
    const f32x4 zero = {0.f, 0.f, 0.f, 0.f};

    float hp;                            // carried h for unit ul

    // prologue: step 1 from ig1 (h0 = 0 -> hg = 0)
    {
        float i0 = ig1[ul], i1 = ig1[HID + ul], i2 = ig1[2 * HID + ul];
        float zg = sigm(i1);
        float ng = tanh_f(fmaf(sigm(i0), bnr, i2));
        hp = ng - zg * ng;               // n + z*(0 - n)
        if (writer) {
            hbuf[1][ul] = (_Float16)hp;  // h for step st=1
            H[ul] = hp;                  // H[0] = h1
        }
    }
    __syncthreads();

    const bool sel0 = (l & 1) != 0;      // select bits for p = l&3
    const bool sel1 = (l & 2) != 0;

    for (int st = 1; st < NSTEPS; ++st) {
        const char* cb = (const char*)&hbuf[st & 1][0];
        // B-fragments: chunk c, lane l -> h[32c + 8*g4 + i] (group-bcast 16B)
        f16x8 b0 = *(const f16x8*)(cb + 16 * g4);
        f16x8 b1 = *(const f16x8*)(cb + 16 * g4 + 64);
        f16x8 b2 = *(const f16x8*)(cb + 16 * g4 + 128);
        f16x8 b3 = *(const f16x8*)(cb + 16 * g4 + 192);
        // 6 independent 4-deep chains, c-major issue (dep distance 6)
        f32x4 d0 = __builtin_amdgcn_mfma_f32_16x16x32_f16(wf00, b0, zero, 0, 0, 0);
        f32x4 d1 = __builtin_amdgcn_mfma_f32_16x16x32_f16(wf10, b0, zero, 0, 0, 0);
        f32x4 d2 = __builtin_amdgcn_mfma_f32_16x16x32_f16(wf20, b0, zero, 0, 0, 0);
        f32x4 d3 = __builtin_amdgcn_mfma_f32_16x16x32_f16(wf30, b0, zero, 0, 0, 0);
        f32x4 d4 = __builtin_amdgcn_mfma_f32_16x16x32_f16(wf40, b0, zero, 0, 0, 0);
        f32x4 d5 = __builtin_amdgcn_mfma_f32_16x16x32_f16(wf50, b0, zero, 0, 0, 0);
        d0 = __builtin_amdgcn_mfma_f32_16x16x32_f16(wf01, b1, d0, 0, 0, 0);
        d1 = __builtin_amdgcn_mfma_f32_16x16x32_f16(wf11, b1, d1, 0, 0, 0);
        d2 = __builtin_amdgcn_mfma_f32_16x16x32_f16(wf21, b1, d2, 0, 0, 0);
        d3 = __builtin_amdgcn_mfma_f32_16x16x32_f16(wf31, b1, d3, 0, 0, 0);
        d4 = __builtin_amdgcn_mfma_f32_16x16x32_f16(wf41, b1, d4, 0, 0, 0);
        d5 = __builtin_amdgcn_mfma_f32_16x16x32_f16(wf51, b1, d5, 0, 0, 0);
        d0 = __builtin_amdgcn_mfma_f32_16x16x32_f16(wf02, b2, d0, 0, 0, 0);
        d1 = __builtin_amdgcn_mfma_f32_16x16x32_f16(wf12, b2, d1, 0, 0, 0);
        d2 = __builtin_amdgcn_mfma_f32_16x16x32_f16(wf22, b2, d2, 0, 0, 0);
        d3 = __builtin_amdgcn_mfma_f32_16x16x32_f16(wf32, b2, d3, 0, 0, 0);
        d4 = __builtin_amdgcn_mfma_f32_16x16x32_f16(wf42, b2, d4, 0, 0, 0);
        d5 = __builtin_amdgcn_mfma_f32_16x16x32_f16(wf52, b2, d5, 0, 0, 0);
        d0 = __builtin_amdgcn_mfma_f32_16x16x32_f16(wf03, b3, d0, 0, 0, 0);
        d1 = __builtin_amdgcn_mfma_f32_16x16x32_f16(wf13, b3, d1, 0, 0, 0);
        d2 = __builtin_amdgcn_mfma_f32_16x16x32_f16(wf23, b3, d2, 0, 0, 0);
        d3 = __builtin_amdgcn_mfma_f32_16x16x32_f16(wf33, b3, d3, 0, 0, 0);
        d4 = __builtin_amdgcn_mfma_f32_16x16x32_f16(wf43, b3, d4, 0, 0, 0);
        d5 = __builtin_amdgcn_mfma_f32_16x16x32_f16(wf53, b3, d5, 0, 0, 0);
        // per-lane component select p = l&3 (constant-index, 3 cndmask each)
#define SEL(b, e) { float s01 = sel0 ? d##b[1] : d##b[0]; \
                    float s23 = sel0 ? d##b[3] : d##b[2]; \
                    e = sel1 ? s23 : s01; }
        float e0, e1, e2, e3, e4, e5;
        SEL(0, e0) SEL(1, e1) SEL(2, e2) SEL(3, e3) SEL(4, e4) SEL(5, e5)
#undef SEL
        // gates for unit ul (16-lane redundancy is SIMD-free)
        float rg = sigm(e0 + gb0 + e3);
        float zg = sigm(e1 + gb1 + e4);
        float ng = tanh_f(e2 + gb2 + rg * (e5 + bnr));
        hp = ng + zg * (hp - ng);
        if (writer) {
            hbuf[(st + 1) & 1][ul] = (_Float16)hp;
            H[(size_t)st * HID + ul] = hp;
        }
        __syncthreads();                 // the single barrier per step
    }
}

// ---------------------------------------------------------------------------
// Kernel 4: out[t][i] = dot(H[t][:], W_dec[i][:]) + b_dec[i]
// GEMM M=4096(t) N=8192(i) K=128, fp32 vector. 64x64 tiles, 256 threads,
// 4x4 micro-tile (strided by 16), XOR-swizzled LDS (64KB total, conflict-free).
// ---------------------------------------------------------------------------
__global__ __launch_bounds__(256) void k_decode(
    const float* __restrict__ H, const float* __restrict__ W_dec,
    const float* __restrict__ b_dec, float* __restrict__ out)
{
    __shared__ float4 As[64 * 32];   // [t][k4], k4 XOR-swizzled by (t&7)
    __shared__ float4 Bs[64 * 32];   // [i][k4]
    const int tid = threadIdx.x;
    const int t0 = blockIdx.y * 64;
    const int i0 = blockIdx.x * 64;
#pragma unroll 8
    for (int j = 0; j < 8; ++j) {
        int f = tid + 256 * j;        // 0..2047 float4s, coalesced
        int t = f >> 5;
        int k4 = f & 31;
        int sw = k4 ^ (t & 7);
        As[t * 32 + sw] = *(const float4*)(H + (size_t)(t0 + t) * HID + 4 * k4);
        Bs[t * 32 + sw] = *(const float4*)(W_dec + (size_t)(i0 + t) * HID + 4 * k4);
    }
    __syncthreads();
    const int tx = tid & 15, ty = tid >> 4;
    const int xa = ty & 7, xb = tx & 7;
    float acc[4][4] = {{0.f}};
#pragma unroll 8
    for (int k4 = 0; k4 < 32; ++k4) {
        float4 a[4], b[4];
        int ia = k4 ^ xa, ib = k4 ^ xb;
#pragma unroll
        for (int u = 0; u < 4; ++u) a[u] = As[(ty + 16 * u) * 32 + ia];
#pragma unroll
        for (int v = 0; v < 4; ++v) b[v] = Bs[(tx + 16 * v) * 32 + ib];
#pragma unroll
        for (int u = 0; u < 4; ++u)
#pragma unroll
            for (int v = 0; v < 4; ++v) {
                acc[u][v] = fmaf(a[u].x, b[v].x, acc[u][v]);
                acc[u][v] = fmaf(a[u].y, b[v].y, acc[u][v]);
                acc[u][v] = fmaf(a[u].z, b[v].z, acc[u][v]);
                acc[u][v] = fmaf(a[u].w, b[v].w, acc[u][v]);
            }
    }
#pragma unroll
    for (int u = 0; u < 4; ++u) {
        int t = t0 + ty + 16 * u;
#pragma unroll
        for (int v = 0; v < 4; ++v) {
            int i = i0 + tx + 16 * v;
            out[(size_t)t * IN_DIM + i] = acc[u][v] + b_dec[i];
        }
    }
}

// ---------------------------------------------------------------------------
extern "C" void kernel_launch(void* const* d_in, const int* in_sizes, int n_in,
                              void* d_out, int out_size, void* d_ws, size_t ws_size,
                              hipStream_t stream)
{
    const float* x0     = (const float*)d_in[0];
    const float* W_enc  = (const float*)d_in[1];
    const float* b_enc  = (const float*)d_in[2];
    const float* W_ih   = (const float*)d_in[3];
    const float* W_hh   = (const float*)d_in[4];
    const float* bias   = (const float*)d_in[5];
    const float* bias_n = (const float*)d_in[6];
    const float* W_dec  = (const float*)d_in[7];
    const float* b_dec  = (const float*)d_in[8];
    float* out = (float*)d_out;

    // workspace layout (floats): ~2.76 MB
    float* ws   = (float*)d_ws;
    float* M    = ws;                 // 16384
    float* cvec = ws + 16384;         // 128
    float* e1   = ws + 16512;         // 128
    float* ig1  = ws + 16640;         // 384
    float* gb   = ws + 17024;         // 768
    float* G    = ws + 17792;         // 98304   (16B-aligned)
    float* H    = ws + 116096;        // 524288  (16B-aligned)
    _Float16* Gp = (_Float16*)(ws + 640384);   // 98304 f16 (192 KB)

    k_precompute_M<<<128, 128, 0, stream>>>(W_enc, W_dec, b_enc, b_dec, x0, M, cvec, e1);
    k_precompute_G<<<768, 128, 0, stream>>>(W_ih, W_hh, bias, M, cvec, e1, G, gb, ig1);
    k_pack<<<384, 256, 0, stream>>>(G, Gp);
    k_recurrence<<<1, 512, 0, stream>>>(Gp, gb, ig1, bias_n, H);
    dim3 grid(IN_DIM / 64, NSTEPS / 64);
    k_decode<<<grid, 256, 0, stream>>>(H, W_dec, b_dec, out);
}

// Round 14
// 2970.054 us; speedup vs baseline: 1.7147x; 1.0046x over previous
//
#include <hip/hip_runtime.h>
#include <math.h>

#define IN_DIM 8192
#define HID 128
#define NSTEPS 4096

typedef _Float16 f16x8 __attribute__((ext_vector_type(8)));
typedef float f32x4 __attribute__((ext_vector_type(4)));

__device__ __forceinline__ float sigm(float x) { return 1.f / (1.f + __expf(-x)); }
__device__ __forceinline__ float tanh_f(float x) {
    x = fminf(fmaxf(x, -15.f), 15.f);          // avoid inf/inf NaN
    float e = __expf(2.f * x);
    return (e - 1.f) / (e + 1.f);
}

// ---------------------------------------------------------------------------
// Kernel 1: M = W_enc @ W_dec  (128x128), cvec = W_enc@b_dec + b_enc,
//           e1 = W_enc@x0 + b_enc.  Grid: 128 blocks (one per row p), 128 thr.
// ---------------------------------------------------------------------------
__global__ __launch_bounds__(128) void k_precompute_M(
    const float* __restrict__ W_enc, const float* __restrict__ W_dec,
    const float* __restrict__ b_enc, const float* __restrict__ b_dec,
    const float* __restrict__ x0,
    float* __restrict__ M, float* __restrict__ cvec, float* __restrict__ e1)
{
    const int p = blockIdx.x;
    const int t = threadIdx.x;              // 0..127 (= output column q)
    __shared__ float wl[128];
    __shared__ float red[256];
    float m0 = 0.f, m1 = 0.f, m2 = 0.f, m3 = 0.f, cacc = 0.f, eacc = 0.f;
    for (int i0 = 0; i0 < IN_DIM; i0 += 128) {
        float w = W_enc[(size_t)p * IN_DIM + i0 + t];   // coalesced
        cacc = fmaf(w, b_dec[i0 + t], cacc);
        eacc = fmaf(w, x0[i0 + t], eacc);
        wl[t] = w;
        __syncthreads();
#pragma unroll 8
        for (int k = 0; k < 128; k += 4) {              // W_dec reads coalesced in t
            m0 = fmaf(wl[k],     W_dec[(size_t)(i0 + k) * HID + t], m0);
            m1 = fmaf(wl[k + 1], W_dec[(size_t)(i0 + k + 1) * HID + t], m1);
            m2 = fmaf(wl[k + 2], W_dec[(size_t)(i0 + k + 2) * HID + t], m2);
            m3 = fmaf(wl[k + 3], W_dec[(size_t)(i0 + k + 3) * HID + t], m3);
        }
        __syncthreads();
    }
    M[p * HID + t] = (m0 + m1) + (m2 + m3);
    red[t] = cacc; red[128 + t] = eacc;
    __syncthreads();
    for (int s = 64; s > 0; s >>= 1) {
        if (t < s) { red[t] += red[t + s]; red[128 + t] += red[128 + t + s]; }
        __syncthreads();
    }
    if (t == 0) { cvec[p] = red[0] + b_enc[p]; e1[p] = red[128] + b_enc[p]; }
}

// ---------------------------------------------------------------------------
// Kernel 2: G rows 0..383 = W_ih@M, rows 384..767 = W_hh (copy).
//           gb[0..383] = W_ih@cvec + bias, gb[384..767] = 0.
//           ig1 = W_ih@e1 + bias.  Grid: 768 blocks, 128 threads.
// ---------------------------------------------------------------------------
__global__ __launch_bounds__(128) void k_precompute_G(
    const float* __restrict__ W_ih, const float* __restrict__ W_hh,
    const float* __restrict__ bias, const float* __restrict__ M,
    const float* __restrict__ cvec, const float* __restrict__ e1,
    float* __restrict__ G, float* __restrict__ gb, float* __restrict__ ig1)
{
    const int r = blockIdx.x;
    const int q = threadIdx.x;
    if (r >= 384) {
        G[(size_t)r * HID + q] = W_hh[(size_t)(r - 384) * HID + q];
        if (q == 0) gb[r] = 0.f;
        return;
    }
    __shared__ float red[256];
    float a0 = 0.f, a1 = 0.f, a2 = 0.f, a3 = 0.f;
#pragma unroll 8
    for (int k = 0; k < HID; k += 4) {   // W_ih[r][k] scalar-uniform, M coalesced
        a0 = fmaf(W_ih[r * HID + k],     M[(k) * HID + q], a0);
        a1 = fmaf(W_ih[r * HID + k + 1], M[(k + 1) * HID + q], a1);
        a2 = fmaf(W_ih[r * HID + k + 2], M[(k + 2) * HID + q], a2);
        a3 = fmaf(W_ih[r * HID + k + 3], M[(k + 3) * HID + q], a3);
    }
    G[(size_t)r * HID + q] = (a0 + a1) + (a2 + a3);
    float wq = W_ih[r * HID + q];
    red[q] = wq * cvec[q];
    red[128 + q] = wq * e1[q];
    __syncthreads();
    for (int s = 64; s > 0; s >>= 1) {
        if (q < s) { red[q] += red[q + s]; red[128 + q] += red[128 + q + s]; }
        __syncthreads();
    }
    if (q == 0) { gb[r] = red[0] + bias[r]; ig1[r] = red[128] + bias[r]; }
}

// ---------------------------------------------------------------------------
// Kernel 2b: pack G into MFMA A-fragments (f16), UNIT-ALIGNED 8-wave layout.
// Wave w owns gate units 16w..16w+15 -> rows 128b+16w..+15 for b=0..5.
// A-layout (v_mfma_f32_16x16x32_f16): lane l elem i = A[l&15][8*(l>>4)+i].
// Gp[((w*24 + b*4 + c)*64 + l)*8 + i] = G[128b+16w+(l&15)][32c+8*(l>>4)+i].
// ---------------------------------------------------------------------------
__global__ __launch_bounds__(256) void k_pack(
    const float* __restrict__ G, _Float16* __restrict__ Gp)
{
    int id = blockIdx.x * 256 + threadIdx.x;   // 0..98303
    int i = id & 7;
    int l = (id >> 3) & 63;
    int frag = id >> 9;                        // 0..191 = w*24 + b*4 + c
    int c = frag & 3;
    int b = (frag >> 2) % 6;
    int w = frag / 24;
    int row = 128 * b + 16 * w + (l & 15);
    int k = 32 * c + ((l >> 4) << 3) + i;
    Gp[id] = (_Float16)G[row * HID + k];
}

// ---------------------------------------------------------------------------
// Kernel 3: sequential GRU scan, gates-from-accumulators. FROZEN R13 (best:
// 2697 us, 658 ns/step). ONE block, 512 thr (8 waves, 2/SIMD). Wave w owns
// UNITS 16w..16w+15; lane l handles ONE unit via 3 cndmask selects (p=l&3);
// one __syncthreads per step; parity-double-buffered 512 B hbuf.
// Weights: 24 A-frags = 96 AGPR ("+a", R8-verified resident mechanism).
// ---------------------------------------------------------------------------
#define WF24(F) F(0,0) F(0,1) F(0,2) F(0,3) F(1,0) F(1,1) F(1,2) F(1,3) \
                F(2,0) F(2,1) F(2,2) F(2,3) F(3,0) F(3,1) F(3,2) F(3,3) \
                F(4,0) F(4,1) F(4,2) F(4,3) F(5,0) F(5,1) F(5,2) F(5,3)

__global__ __launch_bounds__(512, 2) void k_recurrence(
    const _Float16* __restrict__ Gp, const float* __restrict__ gb,
    const float* __restrict__ ig1, const float* __restrict__ bias_n,
    float* __restrict__ H)
{
    const int t = threadIdx.x;           // 0..511
    const int l = t & 63;                // lane
    const int w = t >> 6;                // wave 0..7; units 16w..16w+15
    __shared__ _Float16 hbuf[2][HID];    // parity double-buffered h (256B each)

    // --- stationary weights: 24 MFMA A-fragments -> AGPRs ---
    const f16x8* gpb = (const f16x8*)Gp;
#define DECLW(b,c) f16x8 wf##b##c = gpb[(w * 24 + b * 4 + c) * 64 + l];
    WF24(DECLW)
#undef DECLW
#define PINW(b,c) asm volatile("" : "+a"(wf##b##c));
    WF24(PINW)
#undef PINW

    const int g4 = l >> 4;               // 16-lane group 0..3
    const int ul = 16 * w + 4 * g4 + (l & 3);   // this lane's gate unit
    const bool writer = (l & 12) == 0;   // 16 writers/wave, one per unit

    // per-lane scalars for unit ul
    const float gb0 = gb[ul];
    const float gb1 = gb[HID + ul];
    const float gb2 = gb[2 * HID + ul];
    const float bnr = bias_n[ul];
    const f32x4 zero = {0.f, 0.f, 0.f, 0.f};

    float hp;                            // carried h for unit ul

    // prologue: step 1 from ig1 (h0 = 0 -> hg = 0)
    {
        float i0 = ig1[ul], i1 = ig1[HID + ul], i2 = ig1[2 * HID + ul];
        float zg = sigm(i1);
        float ng = tanh_f(fmaf(sigm(i0), bnr, i2));
        hp = ng - zg * ng;               // n + z*(0 - n)
        if (writer) {
            hbuf[1][ul] = (_Float16)hp;  // h for step st=1
            H[ul] = hp;                  // H[0] = h1
        }
    }
    __syncthreads();

    const bool sel0 = (l & 1) != 0;      // select bits for p = l&3
    const bool sel1 = (l & 2) != 0;

    for (int st = 1; st < NSTEPS; ++st) {
        const char* cb = (const char*)&hbuf[st & 1][0];
        // B-fragments: chunk c, lane l -> h[32c + 8*g4 + i] (group-bcast 16B)
        f16x8 b0 = *(const f16x8*)(cb + 16 * g4);
        f16x8 b1 = *(const f16x8*)(cb + 16 * g4 + 64);
        f16x8 b2 = *(const f16x8*)(cb + 16 * g4 + 128);
        f16x8 b3 = *(const f16x8*)(cb + 16 * g4 + 192);
        // 6 independent 4-deep chains, c-major issue (dep distance 6)
        f32x4 d0 = __builtin_amdgcn_mfma_f32_16x16x32_f16(wf00, b0, zero, 0, 0, 0);
        f32x4 d1 = __builtin_amdgcn_mfma_f32_16x16x32_f16(wf10, b0, zero, 0, 0, 0);
        f32x4 d2 = __builtin_amdgcn_mfma_f32_16x16x32_f16(wf20, b0, zero, 0, 0, 0);
        f32x4 d3 = __builtin_amdgcn_mfma_f32_16x16x32_f16(wf30, b0, zero, 0, 0, 0);
        f32x4 d4 = __builtin_amdgcn_mfma_f32_16x16x32_f16(wf40, b0, zero, 0, 0, 0);
        f32x4 d5 = __builtin_amdgcn_mfma_f32_16x16x32_f16(wf50, b0, zero, 0, 0, 0);
        d0 = __builtin_amdgcn_mfma_f32_16x16x32_f16(wf01, b1, d0, 0, 0, 0);
        d1 = __builtin_amdgcn_mfma_f32_16x16x32_f16(wf11, b1, d1, 0, 0, 0);
        d2 = __builtin_amdgcn_mfma_f32_16x16x32_f16(wf21, b1, d2, 0, 0, 0);
        d3 = __builtin_amdgcn_mfma_f32_16x16x32_f16(wf31, b1, d3, 0, 0, 0);
        d4 = __builtin_amdgcn_mfma_f32_16x16x32_f16(wf41, b1, d4, 0, 0, 0);
        d5 = __builtin_amdgcn_mfma_f32_16x16x32_f16(wf51, b1, d5, 0, 0, 0);
        d0 = __builtin_amdgcn_mfma_f32_16x16x32_f16(wf02, b2, d0, 0, 0, 0);
        d1 = __builtin_amdgcn_mfma_f32_16x16x32_f16(wf12, b2, d1, 0, 0, 0);
        d2 = __builtin_amdgcn_mfma_f32_16x16x32_f16(wf22, b2, d2, 0, 0, 0);
        d3 = __builtin_amdgcn_mfma_f32_16x16x32_f16(wf32, b2, d3, 0, 0, 0);
        d4 = __builtin_amdgcn_mfma_f32_16x16x32_f16(wf42, b2, d4, 0, 0, 0);
        d5 = __builtin_amdgcn_mfma_f32_16x16x32_f16(wf52, b2, d5, 0, 0, 0);
        d0 = __builtin_amdgcn_mfma_f32_16x16x32_f16(wf03, b3, d0, 0, 0, 0);
        d1 = __builtin_amdgcn_mfma_f32_16x16x32_f16(wf13, b3, d1, 0, 0, 0);
        d2 = __builtin_amdgcn_mfma_f32_16x16x32_f16(wf23, b3, d2, 0, 0, 0);
        d3 = __builtin_amdgcn_mfma_f32_16x16x32_f16(wf33, b3, d3, 0, 0, 0);
        d4 = __builtin_amdgcn_mfma_f32_16x16x32_f16(wf43, b3, d4, 0, 0, 0);
        d5 = __builtin_amdgcn_mfma_f32_16x16x32_f16(wf53, b3, d5, 0, 0, 0);
        // per-lane component select p = l&3 (constant-index, 3 cndmask each)
#define SEL(b, e) { float s01 = sel0 ? d##b[1] : d##b[0]; \
                    float s23 = sel0 ? d##b[3] : d##b[2]; \
                    e = sel1 ? s23 : s01; }
        float e0, e1, e2, e3, e4, e5;
        SEL(0, e0) SEL(1, e1) SEL(2, e2) SEL(3, e3) SEL(4, e4) SEL(5, e5)
#undef SEL
        // gates for unit ul (16-lane redundancy is SIMD-free)
        float rg = sigm(e0 + gb0 + e3);
        float zg = sigm(e1 + gb1 + e4);
        float ng = tanh_f(e2 + gb2 + rg * (e5 + bnr));
        hp = ng + zg * (hp - ng);
        if (writer) {
            hbuf[(st + 1) & 1][ul] = (_Float16)hp;
            H[(size_t)st * HID + ul] = hp;
        }
        __syncthreads();                 // the single barrier per step
    }
}

// ---------------------------------------------------------------------------
// Kernel 4 (NEW in R14): MFMA f16 decode, zero LDS.
// out[t][i] = dot(H[t][:], W_dec[i][:]) + b_dec[i].
// Block = 64t x 64i, 4 waves; wave w does t-rows [t0+16w, +16).
// A-frag: lane l elem e = H[t0+16w+(l&15)][32c+8*(l>>4)+e]      (f32->f16)
// B-frag: lane l elem e = W_dec[i0+16ct+(l&15)][32c+8*(l>>4)+e] (f32->f16)
// D-map (m89-verified): lane l reg p -> row 4*(l>>4)+p, col l&15.
// H (2MB) and W_dec (4MB) are L3-resident across block reuse; floor = the
// 128 MB out write (~20us) + L3 reads.
// ---------------------------------------------------------------------------
__global__ __launch_bounds__(256) void k_decode(
    const float* __restrict__ H, const float* __restrict__ W_dec,
    const float* __restrict__ b_dec, float* __restrict__ out)
{
    const int tid = threadIdx.x;
    const int l = tid & 63;
    const int w = tid >> 6;                    // wave 0..3
    const int t0 = blockIdx.y * 64 + 16 * w;   // wave's 16 t-rows
    const int i0 = blockIdx.x * 64;
    const int r = l & 15;
    const int g = l >> 4;

    f32x4 acc0 = {0.f, 0.f, 0.f, 0.f};
    f32x4 acc1 = {0.f, 0.f, 0.f, 0.f};
    f32x4 acc2 = {0.f, 0.f, 0.f, 0.f};
    f32x4 acc3 = {0.f, 0.f, 0.f, 0.f};

#define CVT8(dst, lo, hi) f16x8 dst; \
    dst[0] = (_Float16)lo.x; dst[1] = (_Float16)lo.y; \
    dst[2] = (_Float16)lo.z; dst[3] = (_Float16)lo.w; \
    dst[4] = (_Float16)hi.x; dst[5] = (_Float16)hi.y; \
    dst[6] = (_Float16)hi.z; dst[7] = (_Float16)hi.w;

#pragma unroll
    for (int c = 0; c < 4; ++c) {
        const float* ap = H + (size_t)(t0 + r) * HID + 32 * c + 8 * g;
        float4 alo = *(const float4*)ap;
        float4 ahi = *(const float4*)(ap + 4);
        CVT8(af, alo, ahi)
        const float* bp0 = W_dec + (size_t)(i0 + r) * HID + 32 * c + 8 * g;
        {
            float4 blo = *(const float4*)bp0;
            float4 bhi = *(const float4*)(bp0 + 4);
            CVT8(bf, blo, bhi)
            acc0 = __builtin_amdgcn_mfma_f32_16x16x32_f16(af, bf, acc0, 0, 0, 0);
        }
        {
            const float* bp = bp0 + (size_t)16 * HID;
            float4 blo = *(const float4*)bp;
            float4 bhi = *(const float4*)(bp + 4);
            CVT8(bf, blo, bhi)
            acc1 = __builtin_amdgcn_mfma_f32_16x16x32_f16(af, bf, acc1, 0, 0, 0);
        }
        {
            const float* bp = bp0 + (size_t)32 * HID;
            float4 blo = *(const float4*)bp;
            float4 bhi = *(const float4*)(bp + 4);
            CVT8(bf, blo, bhi)
            acc2 = __builtin_amdgcn_mfma_f32_16x16x32_f16(af, bf, acc2, 0, 0, 0);
        }
        {
            const float* bp = bp0 + (size_t)48 * HID;
            float4 blo = *(const float4*)bp;
            float4 bhi = *(const float4*)(bp + 4);
            CVT8(bf, blo, bhi)
            acc3 = __builtin_amdgcn_mfma_f32_16x16x32_f16(af, bf, acc3, 0, 0, 0);
        }
    }
#undef CVT8

    // epilogue: lane l reg p -> out[t0 + 4g + p][i0 + 16*ct + r]
#define EPI(ct, acc) { \
        float bd = b_dec[i0 + 16 * ct + r]; \
        out[(size_t)(t0 + 4 * g + 0) * IN_DIM + i0 + 16 * ct + r] = acc[0] + bd; \
        out[(size_t)(t0 + 4 * g + 1) * IN_DIM + i0 + 16 * ct + r] = acc[1] + bd; \
        out[(size_t)(t0 + 4 * g + 2) * IN_DIM + i0 + 16 * ct + r] = acc[2] + bd; \
        out[(size_t)(t0 + 4 * g + 3) * IN_DIM + i0 + 16 * ct + r] = acc[3] + bd; }
    EPI(0, acc0) EPI(1, acc1) EPI(2, acc2) EPI(3, acc3)
#undef EPI
}

// ---------------------------------------------------------------------------
extern "C" void kernel_launch(void* const* d_in, const int* in_sizes, int n_in,
                              void* d_out, int out_size, void* d_ws, size_t ws_size,
                              hipStream_t stream)
{
    const float* x0     = (const float*)d_in[0];
    const float* W_enc  = (const float*)d_in[1];
    const float* b_enc  = (const float*)d_in[2];
    const float* W_ih   = (const float*)d_in[3];
    const float* W_hh   = (const float*)d_in[4];
    const float* bias   = (const float*)d_in[5];
    const float* bias_n = (const float*)d_in[6];
    const float* W_dec  = (const float*)d_in[7];
    const float* b_dec  = (const float*)d_in[8];
    float* out = (float*)d_out;

    // workspace layout (floats): ~2.76 MB
    float* ws   = (float*)d_ws;
    float* M    = ws;                 // 16384
    float* cvec = ws + 16384;         // 128
    float* e1   = ws + 16512;         // 128
    float* ig1  = ws + 16640;         // 384
    float* gb   = ws + 17024;         // 768
    float* G    = ws + 17792;         // 98304   (16B-aligned)
    float* H    = ws + 116096;        // 524288  (16B-aligned)
    _Float16* Gp = (_Float16*)(ws + 640384);   // 98304 f16 (192 KB)

    k_precompute_M<<<128, 128, 0, stream>>>(W_enc, W_dec, b_enc, b_dec, x0, M, cvec, e1);
    k_precompute_G<<<768, 128, 0, stream>>>(W_ih, W_hh, bias, M, cvec, e1, G, gb, ig1);
    k_pack<<<384, 256, 0, stream>>>(G, Gp);
    k_recurrence<<<1, 512, 0, stream>>>(Gp, gb, ig1, bias_n, H);
    dim3 grid(IN_DIM / 64, NSTEPS / 64);
    k_decode<<<grid, 256, 0, stream>>>(H, W_dec, b_dec, out);
}

// Round 15
// 2690.343 us; speedup vs baseline: 1.8930x; 1.1040x over previous
//
#include <hip/hip_runtime.h>
#include <math.h>

#define IN_DIM 8192
#define HID 128
#define NSTEPS 4096

typedef _Float16 f16x8 __attribute__((ext_vector_type(8)));
typedef float f32x4 __attribute__((ext_vector_type(4)));

__device__ __forceinline__ float frcp(float x) { return __builtin_amdgcn_rcpf(x); }
__device__ __forceinline__ float sigm(float x) { return frcp(1.f + __expf(-x)); }
__device__ __forceinline__ float tanh_f(float x) {
    x = fminf(fmaxf(x, -15.f), 15.f);          // avoid inf/inf NaN
    float e = __expf(2.f * x);
    return (e - 1.f) * frcp(e + 1.f);
}

// ---------------------------------------------------------------------------
// Kernel 1: M = W_enc @ W_dec  (128x128), cvec = W_enc@b_dec + b_enc,
//           e1 = W_enc@x0 + b_enc.  Grid: 128 blocks (one per row p), 128 thr.
// ---------------------------------------------------------------------------
__global__ __launch_bounds__(128) void k_precompute_M(
    const float* __restrict__ W_enc, const float* __restrict__ W_dec,
    const float* __restrict__ b_enc, const float* __restrict__ b_dec,
    const float* __restrict__ x0,
    float* __restrict__ M, float* __restrict__ cvec, float* __restrict__ e1)
{
    const int p = blockIdx.x;
    const int t = threadIdx.x;              // 0..127 (= output column q)
    __shared__ float wl[128];
    __shared__ float red[256];
    float m0 = 0.f, m1 = 0.f, m2 = 0.f, m3 = 0.f, cacc = 0.f, eacc = 0.f;
    for (int i0 = 0; i0 < IN_DIM; i0 += 128) {
        float w = W_enc[(size_t)p * IN_DIM + i0 + t];   // coalesced
        cacc = fmaf(w, b_dec[i0 + t], cacc);
        eacc = fmaf(w, x0[i0 + t], eacc);
        wl[t] = w;
        __syncthreads();
#pragma unroll 8
        for (int k = 0; k < 128; k += 4) {              // W_dec reads coalesced in t
            m0 = fmaf(wl[k],     W_dec[(size_t)(i0 + k) * HID + t], m0);
            m1 = fmaf(wl[k + 1], W_dec[(size_t)(i0 + k + 1) * HID + t], m1);
            m2 = fmaf(wl[k + 2], W_dec[(size_t)(i0 + k + 2) * HID + t], m2);
            m3 = fmaf(wl[k + 3], W_dec[(size_t)(i0 + k + 3) * HID + t], m3);
        }
        __syncthreads();
    }
    M[p * HID + t] = (m0 + m1) + (m2 + m3);
    red[t] = cacc; red[128 + t] = eacc;
    __syncthreads();
    for (int s = 64; s > 0; s >>= 1) {
        if (t < s) { red[t] += red[t + s]; red[128 + t] += red[128 + t + s]; }
        __syncthreads();
    }
    if (t == 0) { cvec[p] = red[0] + b_enc[p]; e1[p] = red[128] + b_enc[p]; }
}

// ---------------------------------------------------------------------------
// Kernel 2: G rows 0..383 = W_ih@M, rows 384..767 = W_hh (copy).
//           gb[0..383] = W_ih@cvec + bias, gb[384..767] = 0.
//           ig1 = W_ih@e1 + bias.  Grid: 768 blocks, 128 threads.
// ---------------------------------------------------------------------------
__global__ __launch_bounds__(128) void k_precompute_G(
    const float* __restrict__ W_ih, const float* __restrict__ W_hh,
    const float* __restrict__ bias, const float* __restrict__ M,
    const float* __restrict__ cvec, const float* __restrict__ e1,
    float* __restrict__ G, float* __restrict__ gb, float* __restrict__ ig1)
{
    const int r = blockIdx.x;
    const int q = threadIdx.x;
    if (r >= 384) {
        G[(size_t)r * HID + q] = W_hh[(size_t)(r - 384) * HID + q];
        if (q == 0) gb[r] = 0.f;
        return;
    }
    __shared__ float red[256];
    float a0 = 0.f, a1 = 0.f, a2 = 0.f, a3 = 0.f;
#pragma unroll 8
    for (int k = 0; k < HID; k += 4) {   // W_ih[r][k] scalar-uniform, M coalesced
        a0 = fmaf(W_ih[r * HID + k],     M[(k) * HID + q], a0);
        a1 = fmaf(W_ih[r * HID + k + 1], M[(k + 1) * HID + q], a1);
        a2 = fmaf(W_ih[r * HID + k + 2], M[(k + 2) * HID + q], a2);
        a3 = fmaf(W_ih[r * HID + k + 3], M[(k + 3) * HID + q], a3);
    }
    G[(size_t)r * HID + q] = (a0 + a1) + (a2 + a3);
    float wq = W_ih[r * HID + q];
    red[q] = wq * cvec[q];
    red[128 + q] = wq * e1[q];
    __syncthreads();
    for (int s = 64; s > 0; s >>= 1) {
        if (q < s) { red[q] += red[q + s]; red[128 + q] += red[128 + q + s]; }
        __syncthreads();
    }
    if (q == 0) { gb[r] = red[0] + bias[r]; ig1[r] = red[128] + bias[r]; }
}

// ---------------------------------------------------------------------------
// Kernel 2b: pack G into MFMA A-fragments (f16), UNIT-ALIGNED 8-wave layout.
// Wave w owns gate units 16w..16w+15 -> rows 128b+16w..+15 for b=0..5.
// A-layout (v_mfma_f32_16x16x32_f16): lane l elem i = A[l&15][8*(l>>4)+i].
// Gp[((w*24 + b*4 + c)*64 + l)*8 + i] = G[128b+16w+(l&15)][32c+8*(l>>4)+i].
// ---------------------------------------------------------------------------
__global__ __launch_bounds__(256) void k_pack(
    const float* __restrict__ G, _Float16* __restrict__ Gp)
{
    int id = blockIdx.x * 256 + threadIdx.x;   // 0..98303
    int i = id & 7;
    int l = (id >> 3) & 63;
    int frag = id >> 9;                        // 0..191 = w*24 + b*4 + c
    int c = frag & 3;
    int b = (frag >> 2) % 6;
    int w = frag / 24;
    int row = 128 * b + 16 * w + (l & 15);
    int k = 32 * c + ((l >> 4) << 3) + i;
    Gp[id] = (_Float16)G[row * HID + k];
}

// ---------------------------------------------------------------------------
// Kernel 3: sequential GRU scan, gates-from-accumulators. R13 structure
// (best: 2697 us, 658 ns/step) + R15 tail trims:
//  (a) v_rcp_f32 instead of IEEE divides in sigm/tanh — without fast-math
//      each divide was a ~10-op dependent v_div_* chain; 3 of them sat in
//      the per-step dependent gate chain.
//  (b) gb folded into MFMA C-init of d0/d1/d2 (R11-validated): cinit[p] =
//      gb[128b + 16w + 4*g4 + p] matches the D row map row=4*(l>>4)+p.
// Everything else byte-identical to R13: 8 waves, 24 MFMA/wave, 1-unit/lane
// select (p=l&3), one __syncthreads/step, parity-double-buffered 512B hbuf,
// 24 A-frags = 96 AGPR ("+a"-pinned).
// ---------------------------------------------------------------------------
#define WF24(F) F(0,0) F(0,1) F(0,2) F(0,3) F(1,0) F(1,1) F(1,2) F(1,3) \
                F(2,0) F(2,1) F(2,2) F(2,3) F(3,0) F(3,1) F(3,2) F(3,3) \
                F(4,0) F(4,1) F(4,2) F(4,3) F(5,0) F(5,1) F(5,2) F(5,3)

__global__ __launch_bounds__(512, 2) void k_recurrence(
    const _Float16* __restrict__ Gp, const float* __restrict__ gb,
    const float* __restrict__ ig1, const float* __restrict__ bias_n,
    float* __restrict__ H)
{
    const int t = threadIdx.x;           // 0..511
    const int l = t & 63;                // lane
    const int w = t >> 6;                // wave 0..7; units 16w..16w+15
    __shared__ _Float16 hbuf[2][HID];    // parity double-buffered h (256B each)

    // --- stationary weights: 24 MFMA A-fragments -> AGPRs ---
    const f16x8* gpb = (const f16x8*)Gp;
#define DECLW(b,c) f16x8 wf##b##c = gpb[(w * 24 + b * 4 + c) * 64 + l];
    WF24(DECLW)
#undef DECLW
#define PINW(b,c) asm volatile("" : "+a"(wf##b##c));
    WF24(PINW)
#undef PINW

    const int g4 = l >> 4;               // 16-lane group 0..3
    const int ul = 16 * w + 4 * g4 + (l & 3);   // this lane's gate unit
    const bool writer = (l & 12) == 0;   // 16 writers/wave, one per unit

    // folded bias as C-init (blocks 0..2); element p = gb[128b+16w+4g4+p]
    const f32x4 cb0 = *(const f32x4*)&gb[16 * w + 4 * g4];
    const f32x4 cb1 = *(const f32x4*)&gb[HID + 16 * w + 4 * g4];
    const f32x4 cb2 = *(const f32x4*)&gb[2 * HID + 16 * w + 4 * g4];
    const float bnr = bias_n[ul];
    const f32x4 zero = {0.f, 0.f, 0.f, 0.f};

    float hp;                            // carried h for unit ul

    // prologue: step 1 from ig1 (h0 = 0 -> hg = 0)
    {
        float i0 = ig1[ul], i1 = ig1[HID + ul], i2 = ig1[2 * HID + ul];
        float zg = sigm(i1);
        float ng = tanh_f(fmaf(sigm(i0), bnr, i2));
        hp = ng - zg * ng;               // n + z*(0 - n)
        if (writer) {
            hbuf[1][ul] = (_Float16)hp;  // h for step st=1
            H[ul] = hp;                  // H[0] = h1
        }
    }
    __syncthreads();

    const bool sel0 = (l & 1) != 0;      // select bits for p = l&3
    const bool sel1 = (l & 2) != 0;

    for (int st = 1; st < NSTEPS; ++st) {
        const char* cb = (const char*)&hbuf[st & 1][0];
        // B-fragments: chunk c, lane l -> h[32c + 8*g4 + i] (group-bcast 16B)
        f16x8 b0 = *(const f16x8*)(cb + 16 * g4);
        f16x8 b1 = *(const f16x8*)(cb + 16 * g4 + 64);
        f16x8 b2 = *(const f16x8*)(cb + 16 * g4 + 128);
        f16x8 b3 = *(const f16x8*)(cb + 16 * g4 + 192);
        // 6 independent 4-deep chains, c-major issue (dep distance 6)
        f32x4 d0 = __builtin_amdgcn_mfma_f32_16x16x32_f16(wf00, b0, cb0, 0, 0, 0);
        f32x4 d1 = __builtin_amdgcn_mfma_f32_16x16x32_f16(wf10, b0, cb1, 0, 0, 0);
        f32x4 d2 = __builtin_amdgcn_mfma_f32_16x16x32_f16(wf20, b0, cb2, 0, 0, 0);
        f32x4 d3 = __builtin_amdgcn_mfma_f32_16x16x32_f16(wf30, b0, zero, 0, 0, 0);
        f32x4 d4 = __builtin_amdgcn_mfma_f32_16x16x32_f16(wf40, b0, zero, 0, 0, 0);
        f32x4 d5 = __builtin_amdgcn_mfma_f32_16x16x32_f16(wf50, b0, zero, 0, 0, 0);
        d0 = __builtin_amdgcn_mfma_f32_16x16x32_f16(wf01, b1, d0, 0, 0, 0);
        d1 = __builtin_amdgcn_mfma_f32_16x16x32_f16(wf11, b1, d1, 0, 0, 0);
        d2 = __builtin_amdgcn_mfma_f32_16x16x32_f16(wf21, b1, d2, 0, 0, 0);
        d3 = __builtin_amdgcn_mfma_f32_16x16x32_f16(wf31, b1, d3, 0, 0, 0);
        d4 = __builtin_amdgcn_mfma_f32_16x16x32_f16(wf41, b1, d4, 0, 0, 0);
        d5 = __builtin_amdgcn_mfma_f32_16x16x32_f16(wf51, b1, d5, 0, 0, 0);
        d0 = __builtin_amdgcn_mfma_f32_16x16x32_f16(wf02, b2, d0, 0, 0, 0);
        d1 = __builtin_amdgcn_mfma_f32_16x16x32_f16(wf12, b2, d1, 0, 0, 0);
        d2 = __builtin_amdgcn_mfma_f32_16x16x32_f16(wf22, b2, d2, 0, 0, 0);
        d3 = __builtin_amdgcn_mfma_f32_16x16x32_f16(wf32, b2, d3, 0, 0, 0);
        d4 = __builtin_amdgcn_mfma_f32_16x16x32_f16(wf42, b2, d4, 0, 0, 0);
        d5 = __builtin_amdgcn_mfma_f32_16x16x32_f16(wf52, b2, d5, 0, 0, 0);
        d0 = __builtin_amdgcn_mfma_f32_16x16x32_f16(wf03, b3, d0, 0, 0, 0);
        d1 = __builtin_amdgcn_mfma_f32_16x16x32_f16(wf13, b3, d1, 0, 0, 0);
        d2 = __builtin_amdgcn_mfma_f32_16x16x32_f16(wf23, b3, d2, 0, 0, 0);
        d3 = __builtin_amdgcn_mfma_f32_16x16x32_f16(wf33, b3, d3, 0, 0, 0);
        d4 = __builtin_amdgcn_mfma_f32_16x16x32_f16(wf43, b3, d4, 0, 0, 0);
        d5 = __builtin_amdgcn_mfma_f32_16x16x32_f16(wf53, b3, d5, 0, 0, 0);
        // per-lane component select p = l&3 (constant-index, 3 cndmask each)
#define SEL(b, e) { float s01 = sel0 ? d##b[1] : d##b[0]; \
                    float s23 = sel0 ? d##b[3] : d##b[2]; \
                    e = sel1 ? s23 : s01; }
        float e0, e1, e2, e3, e4, e5;
        SEL(0, e0) SEL(1, e1) SEL(2, e2) SEL(3, e3) SEL(4, e4) SEL(5, e5)
#undef SEL
        // gates for unit ul (gb already in e0/e1/e2 via C-init)
        float rg = sigm(e0 + e3);
        float zg = sigm(e1 + e4);
        float ng = tanh_f(e2 + rg * (e5 + bnr));
        hp = ng + zg * (hp - ng);
        if (writer) {
            hbuf[(st + 1) & 1][ul] = (_Float16)hp;
            H[(size_t)st * HID + ul] = hp;
        }
        __syncthreads();                 // the single barrier per step
    }
}

// ---------------------------------------------------------------------------
// Kernel 4: MFMA f16 decode, zero LDS (R14-verified, absmax 2e-3).
// out[t][i] = dot(H[t][:], W_dec[i][:]) + b_dec[i].
// Block = 64t x 64i, 4 waves; wave w does t-rows [t0+16w, +16).
// ---------------------------------------------------------------------------
__global__ __launch_bounds__(256) void k_decode(
    const float* __restrict__ H, const float* __restrict__ W_dec,
    const float* __restrict__ b_dec, float* __restrict__ out)
{
    const int tid = threadIdx.x;
    const int l = tid & 63;
    const int w = tid >> 6;                    // wave 0..3
    const int t0 = blockIdx.y * 64 + 16 * w;   // wave's 16 t-rows
    const int i0 = blockIdx.x * 64;
    const int r = l & 15;
    const int g = l >> 4;

    f32x4 acc0 = {0.f, 0.f, 0.f, 0.f};
    f32x4 acc1 = {0.f, 0.f, 0.f, 0.f};
    f32x4 acc2 = {0.f, 0.f, 0.f, 0.f};
    f32x4 acc3 = {0.f, 0.f, 0.f, 0.f};

#define CVT8(dst, lo, hi) f16x8 dst; \
    dst[0] = (_Float16)lo.x; dst[1] = (_Float16)lo.y; \
    dst[2] = (_Float16)lo.z; dst[3] = (_Float16)lo.w; \
    dst[4] = (_Float16)hi.x; dst[5] = (_Float16)hi.y; \
    dst[6] = (_Float16)hi.z; dst[7] = (_Float16)hi.w;

#pragma unroll
    for (int c = 0; c < 4; ++c) {
        const float* ap = H + (size_t)(t0 + r) * HID + 32 * c + 8 * g;
        float4 alo = *(const float4*)ap;
        float4 ahi = *(const float4*)(ap + 4);
        CVT8(af, alo, ahi)
        const float* bp0 = W_dec + (size_t)(i0 + r) * HID + 32 * c + 8 * g;
        {
            float4 blo = *(const float4*)bp0;
            float4 bhi = *(const float4*)(bp0 + 4);
            CVT8(bf, blo, bhi)
            acc0 = __builtin_amdgcn_mfma_f32_16x16x32_f16(af, bf, acc0, 0, 0, 0);
        }
        {
            const float* bp = bp0 + (size_t)16 * HID;
            float4 blo = *(const float4*)bp;
            float4 bhi = *(const float4*)(bp + 4);
            CVT8(bf, blo, bhi)
            acc1 = __builtin_amdgcn_mfma_f32_16x16x32_f16(af, bf, acc1, 0, 0, 0);
        }
        {
            const float* bp = bp0 + (size_t)32 * HID;
            float4 blo = *(const float4*)bp;
            float4 bhi = *(const float4*)(bp + 4);
            CVT8(bf, blo, bhi)
            acc2 = __builtin_amdgcn_mfma_f32_16x16x32_f16(af, bf, acc2, 0, 0, 0);
        }
        {
            const float* bp = bp0 + (size_t)48 * HID;
            float4 blo = *(const float4*)bp;
            float4 bhi = *(const float4*)(bp + 4);
            CVT8(bf, blo, bhi)
            acc3 = __builtin_amdgcn_mfma_f32_16x16x32_f16(af, bf, acc3, 0, 0, 0);
        }
    }
#undef CVT8

    // epilogue: lane l reg p -> out[t0 + 4g + p][i0 + 16*ct + r]
#define EPI(ct, acc) { \
        float bd = b_dec[i0 + 16 * ct + r]; \
        out[(size_t)(t0 + 4 * g + 0) * IN_DIM + i0 + 16 * ct + r] = acc[0] + bd; \
        out[(size_t)(t0 + 4 * g + 1) * IN_DIM + i0 + 16 * ct + r] = acc[1] + bd; \
        out[(size_t)(t0 + 4 * g + 2) * IN_DIM + i0 + 16 * ct + r] = acc[2] + bd; \
        out[(size_t)(t0 + 4 * g + 3) * IN_DIM + i0 + 16 * ct + r] = acc[3] + bd; }
    EPI(0, acc0) EPI(1, acc1) EPI(2, acc2) EPI(3, acc3)
#undef EPI
}

// ---------------------------------------------------------------------------
extern "C" void kernel_launch(void* const* d_in, const int* in_sizes, int n_in,
                              void* d_out, int out_size, void* d_ws, size_t ws_size,
                              hipStream_t stream)
{
    const float* x0     = (const float*)d_in[0];
    const float* W_enc  = (const float*)d_in[1];
    const float* b_enc  = (const float*)d_in[2];
    const float* W_ih   = (const float*)d_in[3];
    const float* W_hh   = (const float*)d_in[4];
    const float* bias   = (const float*)d_in[5];
    const float* bias_n = (const float*)d_in[6];
    const float* W_dec  = (const float*)d_in[7];
    const float* b_dec  = (const float*)d_in[8];
    float* out = (float*)d_out;

    // workspace layout (floats): ~2.76 MB
    float* ws   = (float*)d_ws;
    float* M    = ws;                 // 16384
    float* cvec = ws + 16384;         // 128
    float* e1   = ws + 16512;         // 128
    float* ig1  = ws + 16640;         // 384
    float* gb   = ws + 17024;         // 768
    float* G    = ws + 17792;         // 98304   (16B-aligned)
    float* H    = ws + 116096;        // 524288  (16B-aligned)
    _Float16* Gp = (_Float16*)(ws + 640384);   // 98304 f16 (192 KB)

    k_precompute_M<<<128, 128, 0, stream>>>(W_enc, W_dec, b_enc, b_dec, x0, M, cvec, e1);
    k_precompute_G<<<768, 128, 0, stream>>>(W_ih, W_hh, bias, M, cvec, e1, G, gb, ig1);
    k_pack<<<384, 256, 0, stream>>>(G, Gp);
    k_recurrence<<<1, 512, 0, stream>>>(Gp, gb, ig1, bias_n, H);
    dim3 grid(IN_DIM / 64, NSTEPS / 64);
    k_decode<<<grid, 256, 0, stream>>>(H, W_dec, b_dec, out);
}

// Round 16
// 2561.494 us; speedup vs baseline: 1.9882x; 1.0503x over previous
//
#include <hip/hip_runtime.h>
#include <math.h>

#define IN_DIM 8192
#define HID 128
#define NSTEPS 4096

typedef _Float16 f16x8 __attribute__((ext_vector_type(8)));
typedef float f32x4 __attribute__((ext_vector_type(4)));

__device__ __forceinline__ float frcp(float x) { return __builtin_amdgcn_rcpf(x); }
__device__ __forceinline__ float sigm(float x) { return frcp(1.f + __expf(-x)); }
__device__ __forceinline__ float tanh_f(float x) {
    x = fminf(fmaxf(x, -15.f), 15.f);          // avoid inf/inf NaN
    float e = __expf(2.f * x);
    return fmaf(-2.f, frcp(e + 1.f), 1.f);     // (e-1)/(e+1) = 1 - 2/(e+1)
}

// ---------------------------------------------------------------------------
// Kernel 1: M = W_enc @ W_dec  (128x128), cvec = W_enc@b_dec + b_enc,
//           e1 = W_enc@x0 + b_enc.  Grid: 128 blocks (one per row p), 128 thr.
// ---------------------------------------------------------------------------
__global__ __launch_bounds__(128) void k_precompute_M(
    const float* __restrict__ W_enc, const float* __restrict__ W_dec,
    const float* __restrict__ b_enc, const float* __restrict__ b_dec,
    const float* __restrict__ x0,
    float* __restrict__ M, float* __restrict__ cvec, float* __restrict__ e1)
{
    const int p = blockIdx.x;
    const int t = threadIdx.x;              // 0..127 (= output column q)
    __shared__ float wl[128];
    __shared__ float red[256];
    float m0 = 0.f, m1 = 0.f, m2 = 0.f, m3 = 0.f, cacc = 0.f, eacc = 0.f;
    for (int i0 = 0; i0 < IN_DIM; i0 += 128) {
        float w = W_enc[(size_t)p * IN_DIM + i0 + t];   // coalesced
        cacc = fmaf(w, b_dec[i0 + t], cacc);
        eacc = fmaf(w, x0[i0 + t], eacc);
        wl[t] = w;
        __syncthreads();
#pragma unroll 8
        for (int k = 0; k < 128; k += 4) {              // W_dec reads coalesced in t
            m0 = fmaf(wl[k],     W_dec[(size_t)(i0 + k) * HID + t], m0);
            m1 = fmaf(wl[k + 1], W_dec[(size_t)(i0 + k + 1) * HID + t], m1);
            m2 = fmaf(wl[k + 2], W_dec[(size_t)(i0 + k + 2) * HID + t], m2);
            m3 = fmaf(wl[k + 3], W_dec[(size_t)(i0 + k + 3) * HID + t], m3);
        }
        __syncthreads();
    }
    M[p * HID + t] = (m0 + m1) + (m2 + m3);
    red[t] = cacc; red[128 + t] = eacc;
    __syncthreads();
    for (int s = 64; s > 0; s >>= 1) {
        if (t < s) { red[t] += red[t + s]; red[128 + t] += red[128 + t + s]; }
        __syncthreads();
    }
    if (t == 0) { cvec[p] = red[0] + b_enc[p]; e1[p] = red[128] + b_enc[p]; }
}

// ---------------------------------------------------------------------------
// Kernel 2: G rows 0..383 = W_ih@M, rows 384..767 = W_hh (copy).
//           gb[0..383] = W_ih@cvec + bias, gb[384..767] = 0.
//           ig1 = W_ih@e1 + bias.  Grid: 768 blocks, 128 threads.
// ---------------------------------------------------------------------------
__global__ __launch_bounds__(128) void k_precompute_G(
    const float* __restrict__ W_ih, const float* __restrict__ W_hh,
    const float* __restrict__ bias, const float* __restrict__ M,
    const float* __restrict__ cvec, const float* __restrict__ e1,
    float* __restrict__ G, float* __restrict__ gb, float* __restrict__ ig1)
{
    const int r = blockIdx.x;
    const int q = threadIdx.x;
    if (r >= 384) {
        G[(size_t)r * HID + q] = W_hh[(size_t)(r - 384) * HID + q];
        if (q == 0) gb[r] = 0.f;
        return;
    }
    __shared__ float red[256];
    float a0 = 0.f, a1 = 0.f, a2 = 0.f, a3 = 0.f;
#pragma unroll 8
    for (int k = 0; k < HID; k += 4) {   // W_ih[r][k] scalar-uniform, M coalesced
        a0 = fmaf(W_ih[r * HID + k],     M[(k) * HID + q], a0);
        a1 = fmaf(W_ih[r * HID + k + 1], M[(k + 1) * HID + q], a1);
        a2 = fmaf(W_ih[r * HID + k + 2], M[(k + 2) * HID + q], a2);
        a3 = fmaf(W_ih[r * HID + k + 3], M[(k + 3) * HID + q], a3);
    }
    G[(size_t)r * HID + q] = (a0 + a1) + (a2 + a3);
    float wq = W_ih[r * HID + q];
    red[q] = wq * cvec[q];
    red[128 + q] = wq * e1[q];
    __syncthreads();
    for (int s = 64; s > 0; s >>= 1) {
        if (q < s) { red[q] += red[q + s]; red[128 + q] += red[128 + q + s]; }
        __syncthreads();
    }
    if (q == 0) { gb[r] = red[0] + bias[r]; ig1[r] = red[128] + bias[r]; }
}

// ---------------------------------------------------------------------------
// Kernel 2b: pack G into MFMA A-fragments (f16), UNIT-ALIGNED 8-wave layout.
// Wave w owns gate units 16w..16w+15 -> rows 128b+16w..+15 for b=0..5.
// A-layout (v_mfma_f32_16x16x32_f16): lane l elem i = A[l&15][8*(l>>4)+i].
// Gp[((w*24 + b*4 + c)*64 + l)*8 + i] = G[128b+16w+(l&15)][32c+8*(l>>4)+i].
// ---------------------------------------------------------------------------
__global__ __launch_bounds__(256) void k_pack(
    const float* __restrict__ G, _Float16* __restrict__ Gp)
{
    int id = blockIdx.x * 256 + threadIdx.x;   // 0..98303
    int i = id & 7;
    int l = (id >> 3) & 63;
    int frag = id >> 9;                        // 0..191 = w*24 + b*4 + c
    int c = frag & 3;
    int b = (frag >> 2) % 6;
    int w = frag / 24;
    int row = 128 * b + 16 * w + (l & 15);
    int k = 32 * c + ((l >> 4) << 3) + i;
    Gp[id] = (_Float16)G[row * HID + k];
}

// ---------------------------------------------------------------------------
// Kernel 3: sequential GRU scan, gates-from-accumulators. R15 structure
// (2407 us, 588 ns/step) + R16 surgical items:
//  (a) s_setprio(1) around the MFMA cluster (T5): 2 waves/SIMD de-phase
//      within a step (one in gate-VALU tail while the other issues MFMA) —
//      the role-diversity regime where setprio paid on 8-phase GEMM (m218b).
//  (b) dependency-ordered chain issue d0,d3 -> d2,d5 -> d1,d4: gates consume
//      rg=f(d0,d3) first, ng=f(d2,d5) next, zg=f(d1,d4) last — the gate
//      chain starts as soon as its needed accumulators retire.
//  (c) tanh via 1 - 2*rcp(e+1) (one fewer dependent op).
// Everything else byte-identical to R15.
// ---------------------------------------------------------------------------
#define WF24(F) F(0,0) F(0,1) F(0,2) F(0,3) F(1,0) F(1,1) F(1,2) F(1,3) \
                F(2,0) F(2,1) F(2,2) F(2,3) F(3,0) F(3,1) F(3,2) F(3,3) \
                F(4,0) F(4,1) F(4,2) F(4,3) F(5,0) F(5,1) F(5,2) F(5,3)

__global__ __launch_bounds__(512, 2) void k_recurrence(
    const _Float16* __restrict__ Gp, const float* __restrict__ gb,
    const float* __restrict__ ig1, const float* __restrict__ bias_n,
    float* __restrict__ H)
{
    const int t = threadIdx.x;           // 0..511
    const int l = t & 63;                // lane
    const int w = t >> 6;                // wave 0..7; units 16w..16w+15
    __shared__ _Float16 hbuf[2][HID];    // parity double-buffered h (256B each)

    // --- stationary weights: 24 MFMA A-fragments -> AGPRs ---
    const f16x8* gpb = (const f16x8*)Gp;
#define DECLW(b,c) f16x8 wf##b##c = gpb[(w * 24 + b * 4 + c) * 64 + l];
    WF24(DECLW)
#undef DECLW
#define PINW(b,c) asm volatile("" : "+a"(wf##b##c));
    WF24(PINW)
#undef PINW

    const int g4 = l >> 4;               // 16-lane group 0..3
    const int ul = 16 * w + 4 * g4 + (l & 3);   // this lane's gate unit
    const bool writer = (l & 12) == 0;   // 16 writers/wave, one per unit

    // folded bias as C-init (blocks 0..2); element p = gb[128b+16w+4g4+p]
    const f32x4 cb0 = *(const f32x4*)&gb[16 * w + 4 * g4];
    const f32x4 cb1 = *(const f32x4*)&gb[HID + 16 * w + 4 * g4];
    const f32x4 cb2 = *(const f32x4*)&gb[2 * HID + 16 * w + 4 * g4];
    const float bnr = bias_n[ul];
    const f32x4 zero = {0.f, 0.f, 0.f, 0.f};

    float hp;                            // carried h for unit ul

    // prologue: step 1 from ig1 (h0 = 0 -> hg = 0)
    {
        float i0 = ig1[ul], i1 = ig1[HID + ul], i2 = ig1[2 * HID + ul];
        float zg = sigm(i1);
        float ng = tanh_f(fmaf(sigm(i0), bnr, i2));
        hp = ng - zg * ng;               // n + z*(0 - n)
        if (writer) {
            hbuf[1][ul] = (_Float16)hp;  // h for step st=1
            H[ul] = hp;                  // H[0] = h1
        }
    }
    __syncthreads();

    const bool sel0 = (l & 1) != 0;      // select bits for p = l&3
    const bool sel1 = (l & 2) != 0;

    for (int st = 1; st < NSTEPS; ++st) {
        const char* cb = (const char*)&hbuf[st & 1][0];
        // B-fragments: chunk c, lane l -> h[32c + 8*g4 + i] (group-bcast 16B)
        f16x8 b0 = *(const f16x8*)(cb + 16 * g4);
        f16x8 b1 = *(const f16x8*)(cb + 16 * g4 + 64);
        f16x8 b2 = *(const f16x8*)(cb + 16 * g4 + 128);
        f16x8 b3 = *(const f16x8*)(cb + 16 * g4 + 192);
        __builtin_amdgcn_s_setprio(1);
        // 6 independent 4-deep chains; issue order (d0,d3),(d2,d5),(d1,d4)
        // matches gate consumption order rg -> ng -> zg.
        f32x4 d0 = __builtin_amdgcn_mfma_f32_16x16x32_f16(wf00, b0, cb0, 0, 0, 0);
        f32x4 d3 = __builtin_amdgcn_mfma_f32_16x16x32_f16(wf30, b0, zero, 0, 0, 0);
        f32x4 d2 = __builtin_amdgcn_mfma_f32_16x16x32_f16(wf20, b0, cb2, 0, 0, 0);
        f32x4 d5 = __builtin_amdgcn_mfma_f32_16x16x32_f16(wf50, b0, zero, 0, 0, 0);
        f32x4 d1 = __builtin_amdgcn_mfma_f32_16x16x32_f16(wf10, b0, cb1, 0, 0, 0);
        f32x4 d4 = __builtin_amdgcn_mfma_f32_16x16x32_f16(wf40, b0, zero, 0, 0, 0);
        d0 = __builtin_amdgcn_mfma_f32_16x16x32_f16(wf01, b1, d0, 0, 0, 0);
        d3 = __builtin_amdgcn_mfma_f32_16x16x32_f16(wf31, b1, d3, 0, 0, 0);
        d2 = __builtin_amdgcn_mfma_f32_16x16x32_f16(wf21, b1, d2, 0, 0, 0);
        d5 = __builtin_amdgcn_mfma_f32_16x16x32_f16(wf51, b1, d5, 0, 0, 0);
        d1 = __builtin_amdgcn_mfma_f32_16x16x32_f16(wf11, b1, d1, 0, 0, 0);
        d4 = __builtin_amdgcn_mfma_f32_16x16x32_f16(wf41, b1, d4, 0, 0, 0);
        d0 = __builtin_amdgcn_mfma_f32_16x16x32_f16(wf02, b2, d0, 0, 0, 0);
        d3 = __builtin_amdgcn_mfma_f32_16x16x32_f16(wf32, b2, d3, 0, 0, 0);
        d2 = __builtin_amdgcn_mfma_f32_16x16x32_f16(wf22, b2, d2, 0, 0, 0);
        d5 = __builtin_amdgcn_mfma_f32_16x16x32_f16(wf52, b2, d5, 0, 0, 0);
        d1 = __builtin_amdgcn_mfma_f32_16x16x32_f16(wf12, b2, d1, 0, 0, 0);
        d4 = __builtin_amdgcn_mfma_f32_16x16x32_f16(wf42, b2, d4, 0, 0, 0);
        d0 = __builtin_amdgcn_mfma_f32_16x16x32_f16(wf03, b3, d0, 0, 0, 0);
        d3 = __builtin_amdgcn_mfma_f32_16x16x32_f16(wf33, b3, d3, 0, 0, 0);
        d2 = __builtin_amdgcn_mfma_f32_16x16x32_f16(wf23, b3, d2, 0, 0, 0);
        d5 = __builtin_amdgcn_mfma_f32_16x16x32_f16(wf53, b3, d5, 0, 0, 0);
        d1 = __builtin_amdgcn_mfma_f32_16x16x32_f16(wf13, b3, d1, 0, 0, 0);
        d4 = __builtin_amdgcn_mfma_f32_16x16x32_f16(wf43, b3, d4, 0, 0, 0);
        __builtin_amdgcn_s_setprio(0);
        // per-lane component select p = l&3 (constant-index, 3 cndmask each)
#define SEL(b, e) { float s01 = sel0 ? d##b[1] : d##b[0]; \
                    float s23 = sel0 ? d##b[3] : d##b[2]; \
                    e = sel1 ? s23 : s01; }
        float e0, e3;
        SEL(0, e0) SEL(3, e3)
        float rg = sigm(e0 + e3);
        float e2, e5;
        SEL(2, e2) SEL(5, e5)
        float ng = tanh_f(e2 + rg * (e5 + bnr));
        float e1v, e4;
        SEL(1, e1v) SEL(4, e4)
#undef SEL
        float zg = sigm(e1v + e4);
        hp = ng + zg * (hp - ng);
        if (writer) {
            hbuf[(st + 1) & 1][ul] = (_Float16)hp;
            H[(size_t)st * HID + ul] = hp;
        }
        __syncthreads();                 // the single barrier per step
    }
}

// ---------------------------------------------------------------------------
// Kernel 4: MFMA f16 decode, zero LDS (R14-verified, absmax 2e-3).
// out[t][i] = dot(H[t][:], W_dec[i][:]) + b_dec[i].
// Block = 64t x 64i, 4 waves; wave w does t-rows [t0+16w, +16).
// ---------------------------------------------------------------------------
__global__ __launch_bounds__(256) void k_decode(
    const float* __restrict__ H, const float* __restrict__ W_dec,
    const float* __restrict__ b_dec, float* __restrict__ out)
{
    const int tid = threadIdx.x;
    const int l = tid & 63;
    const int w = tid >> 6;                    // wave 0..3
    const int t0 = blockIdx.y * 64 + 16 * w;   // wave's 16 t-rows
    const int i0 = blockIdx.x * 64;
    const int r = l & 15;
    const int g = l >> 4;

    f32x4 acc0 = {0.f, 0.f, 0.f, 0.f};
    f32x4 acc1 = {0.f, 0.f, 0.f, 0.f};
    f32x4 acc2 = {0.f, 0.f, 0.f, 0.f};
    f32x4 acc3 = {0.f, 0.f, 0.f, 0.f};

#define CVT8(dst, lo, hi) f16x8 dst; \
    dst[0] = (_Float16)lo.x; dst[1] = (_Float16)lo.y; \
    dst[2] = (_Float16)lo.z; dst[3] = (_Float16)lo.w; \
    dst[4] = (_Float16)hi.x; dst[5] = (_Float16)hi.y; \
    dst[6] = (_Float16)hi.z; dst[7] = (_Float16)hi.w;

#pragma unroll
    for (int c = 0; c < 4; ++c) {
        const float* ap = H + (size_t)(t0 + r) * HID + 32 * c + 8 * g;
        float4 alo = *(const float4*)ap;
        float4 ahi = *(const float4*)(ap + 4);
        CVT8(af, alo, ahi)
        const float* bp0 = W_dec + (size_t)(i0 + r) * HID + 32 * c + 8 * g;
        {
            float4 blo = *(const float4*)bp0;
            float4 bhi = *(const float4*)(bp0 + 4);
            CVT8(bf, blo, bhi)
            acc0 = __builtin_amdgcn_mfma_f32_16x16x32_f16(af, bf, acc0, 0, 0, 0);
        }
        {
            const float* bp = bp0 + (size_t)16 * HID;
            float4 blo = *(const float4*)bp;
            float4 bhi = *(const float4*)(bp + 4);
            CVT8(bf, blo, bhi)
            acc1 = __builtin_amdgcn_mfma_f32_16x16x32_f16(af, bf, acc1, 0, 0, 0);
        }
        {
            const float* bp = bp0 + (size_t)32 * HID;
            float4 blo = *(const float4*)bp;
            float4 bhi = *(const float4*)(bp + 4);
            CVT8(bf, blo, bhi)
            acc2 = __builtin_amdgcn_mfma_f32_16x16x32_f16(af, bf, acc2, 0, 0, 0);
        }
        {
            const float* bp = bp0 + (size_t)48 * HID;
            float4 blo = *(const float4*)bp;
            float4 bhi = *(const float4*)(bp + 4);
            CVT8(bf, blo, bhi)
            acc3 = __builtin_amdgcn_mfma_f32_16x16x32_f16(af, bf, acc3, 0, 0, 0);
        }
    }
#undef CVT8

    // epilogue: lane l reg p -> out[t0 + 4g + p][i0 + 16*ct + r]
#define EPI(ct, acc) { \
        float bd = b_dec[i0 + 16 * ct + r]; \
        out[(size_t)(t0 + 4 * g + 0) * IN_DIM + i0 + 16 * ct + r] = acc[0] + bd; \
        out[(size_t)(t0 + 4 * g + 1) * IN_DIM + i0 + 16 * ct + r] = acc[1] + bd; \
        out[(size_t)(t0 + 4 * g + 2) * IN_DIM + i0 + 16 * ct + r] = acc[2] + bd; \
        out[(size_t)(t0 + 4 * g + 3) * IN_DIM + i0 + 16 * ct + r] = acc[3] + bd; }
    EPI(0, acc0) EPI(1, acc1) EPI(2, acc2) EPI(3, acc3)
#undef EPI
}

// ---------------------------------------------------------------------------
extern "C" void kernel_launch(void* const* d_in, const int* in_sizes, int n_in,
                              void* d_out, int out_size, void* d_ws, size_t ws_size,
                              hipStream_t stream)
{
    const float* x0     = (const float*)d_in[0];
    const float* W_enc  = (const float*)d_in[1];
    const float* b_enc  = (const float*)d_in[2];
    const float* W_ih   = (const float*)d_in[3];
    const float* W_hh   = (const float*)d_in[4];
    const float* bias   = (const float*)d_in[5];
    const float* bias_n = (const float*)d_in[6];
    const float* W_dec  = (const float*)d_in[7];
    const float* b_dec  = (const float*)d_in[8];
    float* out = (float*)d_out;

    // workspace layout (floats): ~2.76 MB
    float* ws   = (float*)d_ws;
    float* M    = ws;                 // 16384
    float* cvec = ws + 16384;         // 128
    float* e1   = ws + 16512;         // 128
    float* ig1  = ws + 16640;         // 384
    float* gb   = ws + 17024;         // 768
    float* G    = ws + 17792;         // 98304   (16B-aligned)
    float* H    = ws + 116096;        // 524288  (16B-aligned)
    _Float16* Gp = (_Float16*)(ws + 640384);   // 98304 f16 (192 KB)

    k_precompute_M<<<128, 128, 0, stream>>>(W_enc, W_dec, b_enc, b_dec, x0, M, cvec, e1);
    k_precompute_G<<<768, 128, 0, stream>>>(W_ih, W_hh, bias, M, cvec, e1, G, gb, ig1);
    k_pack<<<384, 256, 0, stream>>>(G, Gp);
    k_recurrence<<<1, 512, 0, stream>>>(Gp, gb, ig1, bias_n, H);
    dim3 grid(IN_DIM / 64, NSTEPS / 64);
    k_decode<<<grid, 256, 0, stream>>>(H, W_dec, b_dec, out);
}